// Round 5
// baseline (488.829 us; speedup 1.0000x reference)
//
#include <hip/hip_runtime.h>
#include <hip/hip_bf16.h>
#include <stdint.h>

// Problem constants: B=2, S=2048, D=1024, H=16, dk=64
#define NB 2
#define NS 2048
#define ND 1024
#define NH 16
#define DKH 64

typedef __attribute__((ext_vector_type(8))) short bf16x8;   // 8 bf16 = 4 VGPRs
typedef __attribute__((ext_vector_type(4))) float f32x4;
typedef __attribute__((ext_vector_type(8))) unsigned short u16x8;
typedef __attribute__((ext_vector_type(4))) unsigned short u16x4;

__device__ __forceinline__ unsigned short f2bf(float x) {
  union { float f; unsigned int u; } c; c.f = x;
  unsigned int u = c.u;
  unsigned int r = (u + 0x7fffu + ((u >> 16) & 1u)) >> 16;  // round-nearest-even
  return (unsigned short)r;
}

// async global->LDS, 16B per lane; LDS dest is wave-uniform base + lane*16
#define GLOAD_LDS16(gp, lp)                                                     \
  __builtin_amdgcn_global_load_lds(                                             \
      (const __attribute__((address_space(1))) void*)(gp),                      \
      (__attribute__((address_space(3))) void*)(lp), 16, 0, 0)

// ---------------------------------------------------------------- convert ----
// fused fp32->bf16 of {query,key,value,wq,wk,wv,wo}; dsts are CONTIGUOUS in ws
__global__ __launch_bounds__(256) void cvt_all_kernel(
    const float* __restrict__ s0, const float* __restrict__ s1,
    const float* __restrict__ s2, const float* __restrict__ s3,
    const float* __restrict__ s4, const float* __restrict__ s5,
    const float* __restrict__ s6, unsigned short* __restrict__ dst) {
  const int NIN = NB * NS * ND / 8;   // 524288 groups of 8
  const int NWT = ND * ND / 8;        // 131072
  const int TOT = 3 * NIN + 4 * NWT;  // 2097152
  for (int i = blockIdx.x * blockDim.x + threadIdx.x; i < TOT;
       i += gridDim.x * blockDim.x) {
    const float* s; int off;
    if (i < NIN)            { s = s0; off = i; }
    else if (i < 2 * NIN)   { s = s1; off = i - NIN; }
    else if (i < 3 * NIN)   { s = s2; off = i - 2 * NIN; }
    else if (i < 3 * NIN + NWT)     { s = s3; off = i - 3 * NIN; }
    else if (i < 3 * NIN + 2 * NWT) { s = s4; off = i - (3 * NIN + NWT); }
    else if (i < 3 * NIN + 3 * NWT) { s = s5; off = i - (3 * NIN + 2 * NWT); }
    else                            { s = s6; off = i - (3 * NIN + 3 * NWT); }
    const float4* sp = reinterpret_cast<const float4*>(s) + (size_t)off * 2;
    float4 a = sp[0], b = sp[1];
    u16x8 o;
    o[0] = f2bf(a.x); o[1] = f2bf(a.y); o[2] = f2bf(a.z); o[3] = f2bf(a.w);
    o[4] = f2bf(b.x); o[5] = f2bf(b.y); o[6] = f2bf(b.z); o[7] = f2bf(b.w);
    reinterpret_cast<u16x8*>(dst)[i] = o;
  }
}

// mask [B,1,S,S] int32 -> bitmask, 1 bit per (q,k); word = 64 consecutive k
__global__ __launch_bounds__(256) void maskbits_kernel(const int* __restrict__ mask,
                                                       unsigned long long* __restrict__ bits) {
  int i = blockIdx.x * blockDim.x + threadIdx.x;  // one u64 word per thread
  const int4* p = reinterpret_cast<const int4*>(mask + (size_t)i * 64);
  unsigned long long w = 0;
#pragma unroll
  for (int j = 0; j < 16; j++) {
    int4 v = p[j];
    unsigned long long nib = (v.x ? 1ull : 0) | (v.y ? 2ull : 0) |
                             (v.z ? 4ull : 0) | (v.w ? 8ull : 0);
    w |= nib << (j * 4);
  }
  bits[i] = w;
}

// ------------------------------------------------------------- GEMM core ----
// C[BMxBN] = A[BMxK] * Bt[BNxK]^T ; K = 1024, BK=64, global_load_lds w=16.
// THREADS/64 waves arranged (WRN x WCN); wave tile = AM*16 x AN*16.
// SWAP=true computes D^T fragments (operands swapped) for the V-transpose path.
template <bool SWAP, int THREADS, int WCN, int AM, int AN>
__device__ __forceinline__ void gemm_core(const unsigned short* __restrict__ A,
                                          const unsigned short* __restrict__ Bt,
                                          int m0, int n0,
                                          unsigned short* As, unsigned short* Bs,
                                          f32x4 (&acc)[AM][AN]) {
  constexpr int NWAVE = THREADS / 64;
  constexpr int WRN = NWAVE / WCN;
  constexpr int BM = WRN * AM * 16;
  constexpr int BN = WCN * AN * 16;
  constexpr int JA = BM * 64 / (THREADS * 8);
  constexpr int JB = BN * 64 / (THREADS * 8);
  const int tid = threadIdx.x;
  const int w = tid >> 6;
  const int l = tid & 63;
  const int wr = w / WCN, wc = w % WCN;
  const int lr = l & 15, lg = l >> 4;

#pragma unroll
  for (int i = 0; i < AM; i++)
#pragma unroll
    for (int j = 0; j < AN; j++) acc[i][j] = (f32x4){0.f, 0.f, 0.f, 0.f};

  for (int k0 = 0; k0 < ND; k0 += 64) {
    __syncthreads();  // previous tile's compute done before overwrite
#pragma unroll
    for (int j = 0; j < JA; j++) {
      int flat = j * (THREADS * 8) + tid * 8;  // elem index in BMx64 tile
      int row = flat >> 6, col = flat & 63;
      GLOAD_LDS16(A + (size_t)(m0 + row) * ND + k0 + col,
                  As + j * (THREADS * 8) + w * 512);
    }
#pragma unroll
    for (int j = 0; j < JB; j++) {
      int flat = j * (THREADS * 8) + tid * 8;
      int row = flat >> 6, col = flat & 63;
      GLOAD_LDS16(Bt + (size_t)(n0 + row) * ND + k0 + col,
                  Bs + j * (THREADS * 8) + w * 512);
    }
    __syncthreads();  // compiler emits vmcnt(0) drain before barrier
#pragma unroll
    for (int ks = 0; ks < 2; ks++) {
      bf16x8 av[AM], bv[AN];
#pragma unroll
      for (int mi = 0; mi < AM; mi++)
        av[mi] = *reinterpret_cast<const bf16x8*>(
            As + (wr * (AM * 16) + mi * 16 + lr) * 64 + ks * 32 + lg * 8);
#pragma unroll
      for (int ni = 0; ni < AN; ni++)
        bv[ni] = *reinterpret_cast<const bf16x8*>(
            Bs + (wc * (AN * 16) + ni * 16 + lr) * 64 + ks * 32 + lg * 8);
#pragma unroll
      for (int mi = 0; mi < AM; mi++)
#pragma unroll
        for (int ni = 0; ni < AN; ni++)
          acc[mi][ni] = SWAP
              ? __builtin_amdgcn_mfma_f32_16x16x32_bf16(bv[ni], av[mi], acc[mi][ni], 0, 0, 0)
              : __builtin_amdgcn_mfma_f32_16x16x32_bf16(av[mi], bv[ni], acc[mi][ni], 0, 0, 0);
    }
  }
}

// QKV projection: z=0 Q (pre-scaled by 1/sqrt(dk)), z=1 K (store [B,H,S,dk]);
// z=2 V (store transposed [B,H,dk,S])
__global__ __launch_bounds__(256, 2) void qkv_kernel(
    const unsigned short* __restrict__ Xq, const unsigned short* __restrict__ Xk,
    const unsigned short* __restrict__ Xv, const unsigned short* __restrict__ Wq,
    const unsigned short* __restrict__ Wk, const unsigned short* __restrict__ Wv,
    const float* __restrict__ bq, const float* __restrict__ bk,
    const float* __restrict__ bv, unsigned short* __restrict__ Qo,
    unsigned short* __restrict__ Ko, unsigned short* __restrict__ Vt) {
  __shared__ __align__(16) unsigned short As[128 * 64];
  __shared__ __align__(16) unsigned short Bs[128 * 64];
  const int z = blockIdx.z;
  const unsigned short* X = (z == 0) ? Xq : (z == 1) ? Xk : Xv;
  const unsigned short* W = (z == 0) ? Wq : (z == 1) ? Wk : Wv;
  const float* bias = (z == 0) ? bq : (z == 1) ? bk : bv;
  const int m0 = blockIdx.y * 128, n0 = blockIdx.x * 128;
  const int tid = threadIdx.x;
  const int w = tid >> 6, l = tid & 63;
  const int wr = w >> 1, wc = w & 1, lr = l & 15, lg = l >> 4;
  f32x4 acc[4][4];

  if (z < 2) {
    gemm_core<false, 256, 2, 4, 4>(X, W, m0, n0, As, Bs, acc);
    unsigned short* O = (z == 0) ? Qo : Ko;
    const float scl = (z == 0) ? 0.125f : 1.0f;  // fold 1/sqrt(64) into Q
#pragma unroll
    for (int mi = 0; mi < 4; mi++)
#pragma unroll
      for (int ni = 0; ni < 4; ni++)
#pragma unroll
        for (int r = 0; r < 4; r++) {
          int mrow = m0 + wr * 64 + mi * 16 + lg * 4 + r;   // b*S+s
          int ncol = n0 + wc * 64 + ni * 16 + lr;           // h*dk+d
          float y = (acc[mi][ni][r] + bias[ncol]) * scl;
          int bb = mrow >> 11, s = mrow & 2047, hh = ncol >> 6, d = ncol & 63;
          O[(((size_t)(bb * NH + hh)) * NS + s) * DKH + d] = f2bf(y);
        }
  } else {
    gemm_core<true, 256, 2, 4, 4>(X, W, m0, n0, As, Bs, acc);  // D^T fragments
#pragma unroll
    for (int mi = 0; mi < 4; mi++)
#pragma unroll
      for (int ni = 0; ni < 4; ni++)
#pragma unroll
        for (int r = 0; r < 4; r++) {
          int ncol = n0 + wc * 64 + ni * 16 + lg * 4 + r;   // output feature
          int mrow = m0 + wr * 64 + mi * 16 + lr;           // b*S+s (lane-consec)
          float y = acc[mi][ni][r] + bias[ncol];
          int bb = mrow >> 11, s = mrow & 2047, hh = ncol >> 6, d = ncol & 63;
          Vt[(((size_t)(bb * NH + hh)) * DKH + d) * NS + s] = f2bf(y);
        }
  }
}

// output projection: out = O @ wo^T + bo, fp32 out. 8 waves (2x4), wave 64x32.
__global__ __launch_bounds__(512, 2) void outproj_kernel(
    const unsigned short* __restrict__ Oin, const unsigned short* __restrict__ Wo,
    const float* __restrict__ bo, float* __restrict__ out) {
  __shared__ __align__(16) unsigned short As[128 * 64];
  __shared__ __align__(16) unsigned short Bs[128 * 64];
  const int m0 = blockIdx.y * 128, n0 = blockIdx.x * 128;
  const int tid = threadIdx.x;
  const int w = tid >> 6, l = tid & 63;
  const int wr = w >> 2, wc = w & 3, lr = l & 15, lg = l >> 4;
  f32x4 acc[4][2];
  gemm_core<false, 512, 4, 4, 2>(Oin, Wo, m0, n0, As, Bs, acc);
#pragma unroll
  for (int mi = 0; mi < 4; mi++)
#pragma unroll
    for (int ni = 0; ni < 2; ni++)
#pragma unroll
      for (int r = 0; r < 4; r++) {
        int mrow = m0 + wr * 64 + mi * 16 + lg * 4 + r;
        int ncol = n0 + wc * 32 + ni * 16 + lr;
        out[(size_t)mrow * ND + ncol] = acc[mi][ni][r] + bo[ncol];
      }
}

// ----------------------------------------------------------- attention ------
// Block = (b, h, 64 q-rows); 4 waves x 16 q-rows; NO LDS. Swapped QK^T:
// sT = mfma(K, Q) -> lane (lr,lg) holds S[qbase+lr][k = n*16+lg*4+r] : each
// lane owns ONE q-row's scores -> in-register softmax (per-lane scalar
// stats, 2 shuffles per reduce). P re-distributed to the PV B-operand
// fragment (P[q=lr][k=lg*8+t]) with 16 bpermutes + selects. PV computes
// O^T = mfma(V^T, P^T) so acc rows stay q=lr (corr applies per-lane).
// K-tiles double-buffered in registers (prefetch next during softmax).
__device__ __forceinline__ void att_step(
    int kk0, const unsigned short* __restrict__ Kh,
    const unsigned short* __restrict__ Vth,
    const unsigned long long* __restrict__ mrow,
    const bf16x8 (&aQ)[2], bf16x8 (&kbU)[4][2], bf16x8 (&kbP)[4][2],
    f32x4 (&accT)[4], float& mrun, float& lrun, int lr, int lg) {
  // V loads issued early: consumed at the PV at the end of this step
  bf16x8 vb[4][2];
#pragma unroll
  for (int nd = 0; nd < 4; nd++)
#pragma unroll
    for (int ks = 0; ks < 2; ks++)
      vb[nd][ks] = *reinterpret_cast<const bf16x8*>(
          Vth + (size_t)(nd * 16 + lr) * NS + kk0 + ks * 32 + lg * 8);
  unsigned long long w64 = mrow[kk0 >> 6];
  // QK^T (swapped): sT[n][r] = S[qbase+lr][kk0 + n*16 + lg*4 + r]
  f32x4 sT[4];
#pragma unroll
  for (int n = 0; n < 4; n++) sT[n] = (f32x4){0.f, 0.f, 0.f, 0.f};
#pragma unroll
  for (int ks = 0; ks < 2; ks++)
#pragma unroll
    for (int n = 0; n < 4; n++)
      sT[n] = __builtin_amdgcn_mfma_f32_16x16x32_bf16(kbU[n][ks], aQ[ks], sT[n], 0, 0, 0);
  // prefetch next K tile into the other register buffer (wraps at end; unused)
  const int nk = (kk0 + 64) & (NS - 1);
#pragma unroll
  for (int n = 0; n < 4; n++)
#pragma unroll
    for (int ks = 0; ks < 2; ks++)
      kbP[n][ks] = *reinterpret_cast<const bf16x8*>(
          Kh + (size_t)(nk + n * 16 + lr) * DKH + ks * 32 + lg * 8);
  // mask (skipped when the 64-bit word is all ones — the common case)
  if (w64 != ~0ull) {
    unsigned long long wsh = w64 >> (lg * 4);
#pragma unroll
    for (int n = 0; n < 4; n++)
#pragma unroll
      for (int r = 0; r < 4; r++)
        if (!((wsh >> (n * 16 + r)) & 1ull)) sT[n][r] = -1e9f;
  }
  // online softmax, stats per-lane (one q-row per lane)
  float m0 = fmaxf(fmaxf(sT[0][0], sT[0][1]), fmaxf(sT[0][2], sT[0][3]));
  float m1 = fmaxf(fmaxf(sT[1][0], sT[1][1]), fmaxf(sT[1][2], sT[1][3]));
  float m2 = fmaxf(fmaxf(sT[2][0], sT[2][1]), fmaxf(sT[2][2], sT[2][3]));
  float m3 = fmaxf(fmaxf(sT[3][0], sT[3][1]), fmaxf(sT[3][2], sT[3][3]));
  float mx = fmaxf(fmaxf(m0, m1), fmaxf(m2, m3));
  mx = fmaxf(mx, __shfl_xor(mx, 16));
  mx = fmaxf(mx, __shfl_xor(mx, 32));
  float nm = fmaxf(mrun, mx);
  float corr = __expf(mrun - nm);
  mrun = nm;
  float p[4][4];
  float psum = 0.f;
#pragma unroll
  for (int n = 0; n < 4; n++) {
#pragma unroll
    for (int r = 0; r < 4; r++) p[n][r] = __expf(sT[n][r] - nm);
    psum += (p[n][0] + p[n][1]) + (p[n][2] + p[n][3]);
  }
  psum += __shfl_xor(psum, 16);
  psum += __shfl_xor(psum, 32);
  lrun = lrun * corr + psum;
  // pack P pairs to bf16 words: w32[n][h] = (p[n][2h], p[n][2h+1])
  unsigned int w32[4][2];
#pragma unroll
  for (int n = 0; n < 4; n++)
#pragma unroll
    for (int hh = 0; hh < 2; hh++)
      w32[n][hh] = (unsigned)f2bf(p[n][2 * hh]) |
                   ((unsigned)f2bf(p[n][2 * hh + 1]) << 16);
  // redistribute to PV B-operand: lane needs P[q=lr][k=ks*32+lg*8+t]
  //   source lanes lr + 16*(2*(lg&1)) and +16; value n = 2ks + (lg>>1)
  const int src0 = lr + ((lg & 1) << 5);
  const bool hi = (lg & 2) != 0;
  bf16x8 pa[2];
#pragma unroll
  for (int ks = 0; ks < 2; ks++) {
    unsigned a0 = __shfl((int)w32[2 * ks][0], src0, 64);
    unsigned a1 = __shfl((int)w32[2 * ks][1], src0, 64);
    unsigned a2 = __shfl((int)w32[2 * ks][0], src0 + 16, 64);
    unsigned a3 = __shfl((int)w32[2 * ks][1], src0 + 16, 64);
    unsigned b0 = __shfl((int)w32[2 * ks + 1][0], src0, 64);
    unsigned b1 = __shfl((int)w32[2 * ks + 1][1], src0, 64);
    unsigned b2 = __shfl((int)w32[2 * ks + 1][0], src0 + 16, 64);
    unsigned b3 = __shfl((int)w32[2 * ks + 1][1], src0 + 16, 64);
    union { unsigned int u[4]; bf16x8 v; } cv;
    cv.u[0] = hi ? b0 : a0;
    cv.u[1] = hi ? b1 : a1;
    cv.u[2] = hi ? b2 : a2;
    cv.u[3] = hi ? b3 : a3;
    pa[ks] = cv.v;
  }
  // rescale + PV: accT[nd][r] = O[qbase+lr][nd*16+lg*4+r]
#pragma unroll
  for (int nd = 0; nd < 4; nd++) accT[nd] *= corr;
#pragma unroll
  for (int ks = 0; ks < 2; ks++)
#pragma unroll
    for (int nd = 0; nd < 4; nd++)
      accT[nd] = __builtin_amdgcn_mfma_f32_16x16x32_bf16(vb[nd][ks], pa[ks], accT[nd], 0, 0, 0);
}

__global__ __launch_bounds__(256, 4) void attn_kernel(
    const unsigned short* __restrict__ Qg, const unsigned short* __restrict__ Kg,
    const unsigned short* __restrict__ Vtg,
    const unsigned long long* __restrict__ mbits,
    unsigned short* __restrict__ Og) {
  const int tid = threadIdx.x;
  const int w = tid >> 6, l = tid & 63;
  const int lr = l & 15, lg = l >> 4;
  // head-major decode: blocks of the same head share lin%8 -> same XCD (RR)
  const int lin = blockIdx.x;          // 1024 blocks
  const int h = lin & 15;
  const int rest = lin >> 4;           // [0,64)
  const int qblk = rest & 31;
  const int b = rest >> 5;
  const int qbase = qblk * 64 + w * 16;
  const int qa = qbase + lr;           // this lane's q-row

  const unsigned short* Qh = Qg + ((size_t)(b * NH + h)) * NS * DKH;
  const unsigned short* Kh = Kg + ((size_t)(b * NH + h)) * NS * DKH;
  const unsigned short* Vth = Vtg + ((size_t)(b * NH + h)) * DKH * NS;
  const unsigned long long* mrow = mbits + (size_t)(b * NS + qa) * (NS / 64);

  bf16x8 aQ[2];
#pragma unroll
  for (int ks = 0; ks < 2; ks++)
    aQ[ks] = *reinterpret_cast<const bf16x8*>(Qh + (size_t)qa * DKH + ks * 32 + lg * 8);

  f32x4 accT[4];
#pragma unroll
  for (int nd = 0; nd < 4; nd++) accT[nd] = (f32x4){0.f, 0.f, 0.f, 0.f};
  float mrun = -3.0e38f, lrun = 0.f;

  bf16x8 kbA[4][2], kbB[4][2];
#pragma unroll
  for (int n = 0; n < 4; n++)
#pragma unroll
    for (int ks = 0; ks < 2; ks++)
      kbA[n][ks] = *reinterpret_cast<const bf16x8*>(
          Kh + (size_t)(n * 16 + lr) * DKH + ks * 32 + lg * 8);

  for (int it = 0; it < NS / 64; it += 2) {
    att_step(it * 64, Kh, Vth, mrow, aQ, kbA, kbB, accT, mrun, lrun, lr, lg);
    att_step(it * 64 + 64, Kh, Vth, mrow, aQ, kbB, kbA, accT, mrun, lrun, lr, lg);
  }

  // epilogue: O[qa][h*64 + nd*16 + lg*4 + r]
  float inv = 1.0f / lrun;
#pragma unroll
  for (int nd = 0; nd < 4; nd++) {
    u16x4 o;
#pragma unroll
    for (int r = 0; r < 4; r++) o[r] = f2bf(accT[nd][r] * inv);
    *reinterpret_cast<u16x4*>(
        Og + ((size_t)(b * NS + qa)) * ND + h * DKH + nd * 16 + lg * 4) = o;
  }
}

// ---------------------------------------------------------------- launch ----
extern "C" void kernel_launch(void* const* d_in, const int* in_sizes, int n_in,
                              void* d_out, int out_size, void* d_ws, size_t ws_size,
                              hipStream_t stream) {
  (void)in_sizes; (void)n_in; (void)out_size; (void)ws_size;
  const float* query = (const float*)d_in[0];
  const float* key_  = (const float*)d_in[1];
  const float* value = (const float*)d_in[2];
  const int*   mask  = (const int*)d_in[3];
  const float* wq = (const float*)d_in[4];
  const float* bq = (const float*)d_in[5];
  const float* wk = (const float*)d_in[6];
  const float* bk = (const float*)d_in[7];
  const float* wv = (const float*)d_in[8];
  const float* bv = (const float*)d_in[9];
  const float* wo = (const float*)d_in[10];
  const float* bo = (const float*)d_in[11];
  float* out = (float*)d_out;

  char* ws = (char*)d_ws;
  const size_t SZX = (size_t)NB * NS * ND * 2;  // 8 MB (bf16 [4096,1024])
  const size_t SZW = (size_t)ND * ND * 2;       // 2 MB
  unsigned short* xq  = (unsigned short*)(ws);
  unsigned short* wqb = (unsigned short*)(ws + 3 * SZX);
  unsigned short* wkb = (unsigned short*)(ws + 3 * SZX + SZW);
  unsigned short* wvb = (unsigned short*)(ws + 3 * SZX + 2 * SZW);
  unsigned short* wob = (unsigned short*)(ws + 3 * SZX + 3 * SZW);
  unsigned short* xk  = (unsigned short*)(ws + SZX);
  unsigned short* xv  = (unsigned short*)(ws + 2 * SZX);
  unsigned short* Qb  = (unsigned short*)(ws + 3 * SZX + 4 * SZW);
  unsigned short* Kb  = (unsigned short*)(ws + 4 * SZX + 4 * SZW);
  unsigned short* Vt  = (unsigned short*)(ws + 5 * SZX + 4 * SZW);
  unsigned short* Ob  = (unsigned short*)(ws + 6 * SZX + 4 * SZW);
  unsigned long long* mb = (unsigned long long*)(ws + 7 * SZX + 4 * SZW);
  // total ws use: 7*8MB + 8MB + 1MB = 65 MB

  cvt_all_kernel<<<2048, 256, 0, stream>>>(query, key_, value, wq, wk, wv, wo, xq);
  maskbits_kernel<<<512, 256, 0, stream>>>(mask, mb);  // 131072 words

  qkv_kernel<<<dim3(8, 32, 3), 256, 0, stream>>>(xq, xk, xv, wqb, wkb, wvb,
                                                 bq, bk, bv, Qb, Kb, Vt);
  attn_kernel<<<1024, 256, 0, stream>>>(Qb, Kb, Vt, mb, Ob);
  outproj_kernel<<<dim3(8, 32), 512, 0, stream>>>(Ob, wob, bo, out);
}

// Round 7
// 296.512 us; speedup vs baseline: 1.6486x; 1.6486x over previous
//
#include <hip/hip_runtime.h>
#include <hip/hip_bf16.h>
#include <stdint.h>

// Problem constants: B=2, S=2048, D=1024, H=16, dk=64
#define NB 2
#define NS 2048
#define ND 1024
#define NH 16
#define DKH 64

typedef __attribute__((ext_vector_type(8))) short bf16x8;   // 8 bf16 = 4 VGPRs
typedef __attribute__((ext_vector_type(4))) float f32x4;
typedef __attribute__((ext_vector_type(8))) unsigned short u16x8;
typedef __attribute__((ext_vector_type(4))) unsigned short u16x4;

__device__ __forceinline__ unsigned short f2bf(float x) {
  union { float f; unsigned int u; } c; c.f = x;
  unsigned int u = c.u;
  unsigned int r = (u + 0x7fffu + ((u >> 16) & 1u)) >> 16;  // round-nearest-even
  return (unsigned short)r;
}

// async global->LDS, 16B per lane; LDS dest is wave-uniform base + lane*16
#define GLOAD_LDS16(gp, lp)                                                     \
  __builtin_amdgcn_global_load_lds(                                             \
      (const __attribute__((address_space(1))) void*)(gp),                      \
      (__attribute__((address_space(3))) void*)(lp), 16, 0, 0)

// ---------------------------------------------------------------- convert ----
// fused fp32->bf16 of {query,key,value,wq,wk,wv,wo}; dsts are CONTIGUOUS in ws
__global__ __launch_bounds__(256) void cvt_all_kernel(
    const float* __restrict__ s0, const float* __restrict__ s1,
    const float* __restrict__ s2, const float* __restrict__ s3,
    const float* __restrict__ s4, const float* __restrict__ s5,
    const float* __restrict__ s6, unsigned short* __restrict__ dst) {
  const int NIN = NB * NS * ND / 8;   // 524288 groups of 8
  const int NWT = ND * ND / 8;        // 131072
  const int TOT = 3 * NIN + 4 * NWT;  // 2097152
  for (int i = blockIdx.x * blockDim.x + threadIdx.x; i < TOT;
       i += gridDim.x * blockDim.x) {
    const float* s; int off;
    if (i < NIN)            { s = s0; off = i; }
    else if (i < 2 * NIN)   { s = s1; off = i - NIN; }
    else if (i < 3 * NIN)   { s = s2; off = i - 2 * NIN; }
    else if (i < 3 * NIN + NWT)     { s = s3; off = i - 3 * NIN; }
    else if (i < 3 * NIN + 2 * NWT) { s = s4; off = i - (3 * NIN + NWT); }
    else if (i < 3 * NIN + 3 * NWT) { s = s5; off = i - (3 * NIN + 2 * NWT); }
    else                            { s = s6; off = i - (3 * NIN + 3 * NWT); }
    const float4* sp = reinterpret_cast<const float4*>(s) + (size_t)off * 2;
    float4 a = sp[0], b = sp[1];
    u16x8 o;
    o[0] = f2bf(a.x); o[1] = f2bf(a.y); o[2] = f2bf(a.z); o[3] = f2bf(a.w);
    o[4] = f2bf(b.x); o[5] = f2bf(b.y); o[6] = f2bf(b.z); o[7] = f2bf(b.w);
    reinterpret_cast<u16x8*>(dst)[i] = o;
  }
}

// mask [B,1,S,S] int32 -> bitmask, 1 bit per (q,k); word = 64 consecutive k
__global__ __launch_bounds__(256) void maskbits_kernel(const int* __restrict__ mask,
                                                       unsigned long long* __restrict__ bits) {
  int i = blockIdx.x * blockDim.x + threadIdx.x;  // one u64 word per thread
  const int4* p = reinterpret_cast<const int4*>(mask + (size_t)i * 64);
  unsigned long long w = 0;
#pragma unroll
  for (int j = 0; j < 16; j++) {
    int4 v = p[j];
    unsigned long long nib = (v.x ? 1ull : 0) | (v.y ? 2ull : 0) |
                             (v.z ? 4ull : 0) | (v.w ? 8ull : 0);
    w |= nib << (j * 4);
  }
  bits[i] = w;
}

// ------------------------------------------------------------- GEMM core ----
// C[BMxBN] = A[BMxK] * Bt[BNxK]^T ; K = 1024, BK=64, global_load_lds w=16.
// THREADS/64 waves arranged (WRN x WCN); wave tile = AM*16 x AN*16.
// SWAP=true computes D^T fragments (operands swapped) for the V-transpose path.
template <bool SWAP, int THREADS, int WCN, int AM, int AN>
__device__ __forceinline__ void gemm_core(const unsigned short* __restrict__ A,
                                          const unsigned short* __restrict__ Bt,
                                          int m0, int n0,
                                          unsigned short* As, unsigned short* Bs,
                                          f32x4 (&acc)[AM][AN]) {
  constexpr int NWAVE = THREADS / 64;
  constexpr int WRN = NWAVE / WCN;
  constexpr int BM = WRN * AM * 16;
  constexpr int BN = WCN * AN * 16;
  constexpr int JA = BM * 64 / (THREADS * 8);
  constexpr int JB = BN * 64 / (THREADS * 8);
  const int tid = threadIdx.x;
  const int w = tid >> 6;
  const int l = tid & 63;
  const int wr = w / WCN, wc = w % WCN;
  const int lr = l & 15, lg = l >> 4;

#pragma unroll
  for (int i = 0; i < AM; i++)
#pragma unroll
    for (int j = 0; j < AN; j++) acc[i][j] = (f32x4){0.f, 0.f, 0.f, 0.f};

  for (int k0 = 0; k0 < ND; k0 += 64) {
    __syncthreads();  // previous tile's compute done before overwrite
#pragma unroll
    for (int j = 0; j < JA; j++) {
      int flat = j * (THREADS * 8) + tid * 8;  // elem index in BMx64 tile
      int row = flat >> 6, col = flat & 63;
      GLOAD_LDS16(A + (size_t)(m0 + row) * ND + k0 + col,
                  As + j * (THREADS * 8) + w * 512);
    }
#pragma unroll
    for (int j = 0; j < JB; j++) {
      int flat = j * (THREADS * 8) + tid * 8;
      int row = flat >> 6, col = flat & 63;
      GLOAD_LDS16(Bt + (size_t)(n0 + row) * ND + k0 + col,
                  Bs + j * (THREADS * 8) + w * 512);
    }
    __syncthreads();  // compiler emits vmcnt(0) drain before barrier
#pragma unroll
    for (int ks = 0; ks < 2; ks++) {
      bf16x8 av[AM], bv[AN];
#pragma unroll
      for (int mi = 0; mi < AM; mi++)
        av[mi] = *reinterpret_cast<const bf16x8*>(
            As + (wr * (AM * 16) + mi * 16 + lr) * 64 + ks * 32 + lg * 8);
#pragma unroll
      for (int ni = 0; ni < AN; ni++)
        bv[ni] = *reinterpret_cast<const bf16x8*>(
            Bs + (wc * (AN * 16) + ni * 16 + lr) * 64 + ks * 32 + lg * 8);
#pragma unroll
      for (int mi = 0; mi < AM; mi++)
#pragma unroll
        for (int ni = 0; ni < AN; ni++)
          acc[mi][ni] = SWAP
              ? __builtin_amdgcn_mfma_f32_16x16x32_bf16(bv[ni], av[mi], acc[mi][ni], 0, 0, 0)
              : __builtin_amdgcn_mfma_f32_16x16x32_bf16(av[mi], bv[ni], acc[mi][ni], 0, 0, 0);
    }
  }
}

// QKV projection: z=0 Q (pre-scaled by 1/sqrt(dk)), z=1 K (store [B,H,S,dk]);
// z=2 V (store transposed [B,H,dk,S])
__global__ __launch_bounds__(256, 2) void qkv_kernel(
    const unsigned short* __restrict__ Xq, const unsigned short* __restrict__ Xk,
    const unsigned short* __restrict__ Xv, const unsigned short* __restrict__ Wq,
    const unsigned short* __restrict__ Wk, const unsigned short* __restrict__ Wv,
    const float* __restrict__ bq, const float* __restrict__ bk,
    const float* __restrict__ bv, unsigned short* __restrict__ Qo,
    unsigned short* __restrict__ Ko, unsigned short* __restrict__ Vt) {
  __shared__ __align__(16) unsigned short As[128 * 64];
  __shared__ __align__(16) unsigned short Bs[128 * 64];
  const int z = blockIdx.z;
  const unsigned short* X = (z == 0) ? Xq : (z == 1) ? Xk : Xv;
  const unsigned short* W = (z == 0) ? Wq : (z == 1) ? Wk : Wv;
  const float* bias = (z == 0) ? bq : (z == 1) ? bk : bv;
  const int m0 = blockIdx.y * 128, n0 = blockIdx.x * 128;
  const int tid = threadIdx.x;
  const int w = tid >> 6, l = tid & 63;
  const int wr = w >> 1, wc = w & 1, lr = l & 15, lg = l >> 4;
  f32x4 acc[4][4];

  if (z < 2) {
    gemm_core<false, 256, 2, 4, 4>(X, W, m0, n0, As, Bs, acc);
    unsigned short* O = (z == 0) ? Qo : Ko;
    const float scl = (z == 0) ? 0.125f : 1.0f;  // fold 1/sqrt(64) into Q
#pragma unroll
    for (int mi = 0; mi < 4; mi++)
#pragma unroll
      for (int ni = 0; ni < 4; ni++)
#pragma unroll
        for (int r = 0; r < 4; r++) {
          int mrow = m0 + wr * 64 + mi * 16 + lg * 4 + r;   // b*S+s
          int ncol = n0 + wc * 64 + ni * 16 + lr;           // h*dk+d
          float y = (acc[mi][ni][r] + bias[ncol]) * scl;
          int bb = mrow >> 11, s = mrow & 2047, hh = ncol >> 6, d = ncol & 63;
          O[(((size_t)(bb * NH + hh)) * NS + s) * DKH + d] = f2bf(y);
        }
  } else {
    gemm_core<true, 256, 2, 4, 4>(X, W, m0, n0, As, Bs, acc);  // D^T fragments
#pragma unroll
    for (int mi = 0; mi < 4; mi++)
#pragma unroll
      for (int ni = 0; ni < 4; ni++)
#pragma unroll
        for (int r = 0; r < 4; r++) {
          int ncol = n0 + wc * 64 + ni * 16 + lg * 4 + r;   // output feature
          int mrow = m0 + wr * 64 + mi * 16 + lr;           // b*S+s (lane-consec)
          float y = acc[mi][ni][r] + bias[ncol];
          int bb = mrow >> 11, s = mrow & 2047, hh = ncol >> 6, d = ncol & 63;
          Vt[(((size_t)(bb * NH + hh)) * DKH + d) * NS + s] = f2bf(y);
        }
  }
}

// output projection: out = O @ wo^T + bo, fp32 out. 8 waves (2x4), wave 64x32.
__global__ __launch_bounds__(512, 2) void outproj_kernel(
    const unsigned short* __restrict__ Oin, const unsigned short* __restrict__ Wo,
    const float* __restrict__ bo, float* __restrict__ out) {
  __shared__ __align__(16) unsigned short As[128 * 64];
  __shared__ __align__(16) unsigned short Bs[128 * 64];
  const int m0 = blockIdx.y * 128, n0 = blockIdx.x * 128;
  const int tid = threadIdx.x;
  const int w = tid >> 6, l = tid & 63;
  const int wr = w >> 2, wc = w & 3, lr = l & 15, lg = l >> 4;
  f32x4 acc[4][2];
  gemm_core<false, 512, 4, 4, 2>(Oin, Wo, m0, n0, As, Bs, acc);
#pragma unroll
  for (int mi = 0; mi < 4; mi++)
#pragma unroll
    for (int ni = 0; ni < 2; ni++)
#pragma unroll
      for (int r = 0; r < 4; r++) {
        int mrow = m0 + wr * 64 + mi * 16 + lg * 4 + r;
        int ncol = n0 + wc * 32 + ni * 16 + lr;
        out[(size_t)mrow * ND + ncol] = acc[mi][ni][r] + bo[ncol];
      }
}

// ----------------------------------------------------------- attention ------
// Block = (b, h, 128 q-rows); 4 waves x 32 q-rows (2 m-slots of 16).
// K and V^T tiles (64x64 bf16, 8KB each) staged cooperatively in LDS with
// XOR swizzle (chunk ^= row&7), double-buffered; one barrier per K-tile.
// Swapped QK^T (mfma(K,Q)): lane owns one q-row per m-slot -> in-register
// softmax; P redistributed to PV B-operand via 16 bpermutes/m (verified r5).
__global__ __launch_bounds__(256, 3) void attn_kernel(
    const unsigned short* __restrict__ Qg, const unsigned short* __restrict__ Kg,
    const unsigned short* __restrict__ Vtg,
    const unsigned long long* __restrict__ mbits,
    unsigned short* __restrict__ Og) {
  __shared__ __align__(16) unsigned short Ks[2][64 * 64];
  __shared__ __align__(16) unsigned short Vs[2][64 * 64];
  const int tid = threadIdx.x;
  const int w = tid >> 6, l = tid & 63;
  const int lr = l & 15, lg = l >> 4;
  // head-major decode: head h always lands on XCD h%8 (blockIdx RR over XCDs)
  const int lin = blockIdx.x;          // 512 blocks
  const int h = lin & 15;
  const int rest = lin >> 4;           // [0,32)
  const int qblk = rest & 15;          // 16 q-blocks of 128 rows
  const int b = rest >> 4;
  const int qbase = qblk * 128 + w * 32;

  const unsigned short* Qh = Qg + ((size_t)(b * NH + h)) * NS * DKH;
  const unsigned short* Kh = Kg + ((size_t)(b * NH + h)) * NS * DKH;
  const unsigned short* Vth = Vtg + ((size_t)(b * NH + h)) * DKH * NS;
  const unsigned long long* mrowp[2] = {
      mbits + (size_t)(b * NS + qbase + lr) * (NS / 64),
      mbits + (size_t)(b * NS + qbase + 16 + lr) * (NS / 64)};

  // Q fragments, 2 m-slots (Q pre-scaled by 1/sqrt(dk) in qkv)
  bf16x8 aQ[2][2];
#pragma unroll
  for (int m = 0; m < 2; m++)
#pragma unroll
    for (int ks = 0; ks < 2; ks++)
      aQ[m][ks] = *reinterpret_cast<const bf16x8*>(
          Qh + (size_t)(qbase + m * 16 + lr) * DKH + ks * 32 + lg * 8);

  f32x4 accT[2][4];
#pragma unroll
  for (int m = 0; m < 2; m++)
#pragma unroll
    for (int nd = 0; nd < 4; nd++) accT[m][nd] = (f32x4){0.f, 0.f, 0.f, 0.f};
  float mrun[2] = {-3.0e38f, -3.0e38f}, lrun[2] = {0.f, 0.f};

  // cooperative staging: 8KB tile = 512 chunks of 16B; 256 threads x 2 insts.
  // pre-swizzled SOURCE (chunk-in-row ^= row&7) + linear LDS dest + swizzled
  // ds_read => net identity (rule: both-sides-or-neither).
#define STAGE_TILES(bufi, kk0)                                                  \
  {                                                                             \
    _Pragma("unroll") for (int j = 0; j < 2; j++) {                             \
      int c = j * 256 + tid;                                                    \
      int row = c >> 3;                                                         \
      int cr = (c & 7) ^ (row & 7);                                             \
      GLOAD_LDS16(Kh + (size_t)((kk0) + row) * DKH + cr * 8,                    \
                  &Ks[bufi][(size_t)(j * 256 + w * 64) * 8]);                   \
    }                                                                           \
    _Pragma("unroll") for (int j = 0; j < 2; j++) {                             \
      int c = j * 256 + tid;                                                    \
      int row = c >> 3;                                                         \
      int cr = (c & 7) ^ (row & 7);                                             \
      GLOAD_LDS16(Vth + (size_t)row * NS + (kk0) + cr * 8,                      \
                  &Vs[bufi][(size_t)(j * 256 + w * 64) * 8]);                   \
    }                                                                           \
  }

  STAGE_TILES(0, 0)
  __syncthreads();  // compiler drains vmcnt before barrier
  int buf = 0;

  for (int t = 0; t < NS / 64; t++) {
    const int kk0 = t * 64;
    if (t < NS / 64 - 1) STAGE_TILES(buf ^ 1, kk0 + 64)
    unsigned long long w64m[2] = {mrowp[0][t], mrowp[1][t]};
    // K fragments from LDS (shared across both m-slots)
    bf16x8 kb[4][2];
#pragma unroll
    for (int n = 0; n < 4; n++)
#pragma unroll
      for (int ks = 0; ks < 2; ks++)
        kb[n][ks] = *reinterpret_cast<const bf16x8*>(
            &Ks[buf][(size_t)(n * 16 + lr) * 64 +
                     (size_t)(((ks * 4 + lg) ^ (lr & 7)) * 8)]);
    // QK^T: sT[m][n][r] = S[qbase+m*16+lr][kk0 + n*16 + lg*4 + r]
    f32x4 sT[2][4];
#pragma unroll
    for (int m = 0; m < 2; m++)
#pragma unroll
      for (int n = 0; n < 4; n++) sT[m][n] = (f32x4){0.f, 0.f, 0.f, 0.f};
    __builtin_amdgcn_s_setprio(1);
#pragma unroll
    for (int ks = 0; ks < 2; ks++)
#pragma unroll
      for (int m = 0; m < 2; m++)
#pragma unroll
        for (int n = 0; n < 4; n++)
          sT[m][n] = __builtin_amdgcn_mfma_f32_16x16x32_bf16(kb[n][ks], aQ[m][ks],
                                                             sT[m][n], 0, 0, 0);
    __builtin_amdgcn_s_setprio(0);
    // V fragments (LDS reads issued early; consumed after softmax)
    bf16x8 vb[4][2];
#pragma unroll
    for (int nd = 0; nd < 4; nd++)
#pragma unroll
      for (int ks = 0; ks < 2; ks++)
        vb[nd][ks] = *reinterpret_cast<const bf16x8*>(
            &Vs[buf][(size_t)(nd * 16 + lr) * 64 +
                     (size_t)(((ks * 4 + lg) ^ (lr & 7)) * 8)]);

#pragma unroll
    for (int m = 0; m < 2; m++) {
      unsigned long long w64 = w64m[m];
      if (w64 != ~0ull) {
        unsigned long long wsh = w64 >> (lg * 4);
#pragma unroll
        for (int n = 0; n < 4; n++)
#pragma unroll
          for (int r = 0; r < 4; r++)
            if (!((wsh >> (n * 16 + r)) & 1ull)) sT[m][n][r] = -1e9f;
      }
      // online softmax, per-lane stats (one q-row per lane per m-slot)
      float m0 = fmaxf(fmaxf(sT[m][0][0], sT[m][0][1]), fmaxf(sT[m][0][2], sT[m][0][3]));
      float m1 = fmaxf(fmaxf(sT[m][1][0], sT[m][1][1]), fmaxf(sT[m][1][2], sT[m][1][3]));
      float m2 = fmaxf(fmaxf(sT[m][2][0], sT[m][2][1]), fmaxf(sT[m][2][2], sT[m][2][3]));
      float m3 = fmaxf(fmaxf(sT[m][3][0], sT[m][3][1]), fmaxf(sT[m][3][2], sT[m][3][3]));
      float mx = fmaxf(fmaxf(m0, m1), fmaxf(m2, m3));
      mx = fmaxf(mx, __shfl_xor(mx, 16));
      mx = fmaxf(mx, __shfl_xor(mx, 32));
      float nm = fmaxf(mrun[m], mx);
      float corr = __expf(mrun[m] - nm);
      mrun[m] = nm;
      float p[4][4];
      float psum = 0.f;
#pragma unroll
      for (int n = 0; n < 4; n++) {
#pragma unroll
        for (int r = 0; r < 4; r++) p[n][r] = __expf(sT[m][n][r] - nm);
        psum += (p[n][0] + p[n][1]) + (p[n][2] + p[n][3]);
      }
      psum += __shfl_xor(psum, 16);
      psum += __shfl_xor(psum, 32);
      lrun[m] = lrun[m] * corr + psum;
      // pack P pairs to bf16 words: w32[n][hh] = (p[n][2hh], p[n][2hh+1])
      unsigned int w32[4][2];
#pragma unroll
      for (int n = 0; n < 4; n++)
#pragma unroll
        for (int hh = 0; hh < 2; hh++)
          w32[n][hh] = (unsigned)f2bf(p[n][2 * hh]) |
                       ((unsigned)f2bf(p[n][2 * hh + 1]) << 16);
      // redistribute to PV B-operand (verified r5): lane gets P[q=lr][k-slice]
      const int src0 = lr + ((lg & 1) << 5);
      const bool hi = (lg & 2) != 0;
      bf16x8 pa[2];
#pragma unroll
      for (int ks = 0; ks < 2; ks++) {
        unsigned a0 = __shfl((int)w32[2 * ks][0], src0, 64);
        unsigned a1 = __shfl((int)w32[2 * ks][1], src0, 64);
        unsigned a2 = __shfl((int)w32[2 * ks][0], src0 + 16, 64);
        unsigned a3 = __shfl((int)w32[2 * ks][1], src0 + 16, 64);
        unsigned b0 = __shfl((int)w32[2 * ks + 1][0], src0, 64);
        unsigned b1 = __shfl((int)w32[2 * ks + 1][1], src0, 64);
        unsigned b2 = __shfl((int)w32[2 * ks + 1][0], src0 + 16, 64);
        unsigned b3 = __shfl((int)w32[2 * ks + 1][1], src0 + 16, 64);
        union { unsigned int u[4]; bf16x8 v; } cv;
        cv.u[0] = hi ? b0 : a0;
        cv.u[1] = hi ? b1 : a1;
        cv.u[2] = hi ? b2 : a2;
        cv.u[3] = hi ? b3 : a3;
        pa[ks] = cv.v;
      }
      // rescale + PV: accT[m][nd][r] = O[q][d = nd*16 + lg*4 + r]
#pragma unroll
      for (int nd = 0; nd < 4; nd++) accT[m][nd] *= corr;
      __builtin_amdgcn_s_setprio(1);
#pragma unroll
      for (int ks = 0; ks < 2; ks++)
#pragma unroll
        for (int nd = 0; nd < 4; nd++)
          accT[m][nd] = __builtin_amdgcn_mfma_f32_16x16x32_bf16(vb[nd][ks], pa[ks],
                                                                accT[m][nd], 0, 0, 0);
      __builtin_amdgcn_s_setprio(0);
    }
    __syncthreads();  // staging of t+1 drained; all waves done reading buf
    buf ^= 1;
  }
#undef STAGE_TILES

  // epilogue: O[qa][h*64 + nd*16 + lg*4 + r]
#pragma unroll
  for (int m = 0; m < 2; m++) {
    float inv = 1.0f / lrun[m];
    int qa = qbase + m * 16 + lr;
#pragma unroll
    for (int nd = 0; nd < 4; nd++) {
      u16x4 o;
#pragma unroll
      for (int r = 0; r < 4; r++) o[r] = f2bf(accT[m][nd][r] * inv);
      *reinterpret_cast<u16x4*>(
          Og + ((size_t)(b * NS + qa)) * ND + h * DKH + nd * 16 + lg * 4) = o;
    }
  }
}

// ---------------------------------------------------------------- launch ----
extern "C" void kernel_launch(void* const* d_in, const int* in_sizes, int n_in,
                              void* d_out, int out_size, void* d_ws, size_t ws_size,
                              hipStream_t stream) {
  (void)in_sizes; (void)n_in; (void)out_size; (void)ws_size;
  const float* query = (const float*)d_in[0];
  const float* key_  = (const float*)d_in[1];
  const float* value = (const float*)d_in[2];
  const int*   mask  = (const int*)d_in[3];
  const float* wq = (const float*)d_in[4];
  const float* bq = (const float*)d_in[5];
  const float* wk = (const float*)d_in[6];
  const float* bk = (const float*)d_in[7];
  const float* wv = (const float*)d_in[8];
  const float* bv = (const float*)d_in[9];
  const float* wo = (const float*)d_in[10];
  const float* bo = (const float*)d_in[11];
  float* out = (float*)d_out;

  char* ws = (char*)d_ws;
  const size_t SZX = (size_t)NB * NS * ND * 2;  // 8 MB (bf16 [4096,1024])
  const size_t SZW = (size_t)ND * ND * 2;       // 2 MB
  unsigned short* xq  = (unsigned short*)(ws);
  unsigned short* xk  = (unsigned short*)(ws + SZX);
  unsigned short* xv  = (unsigned short*)(ws + 2 * SZX);
  unsigned short* wqb = (unsigned short*)(ws + 3 * SZX);
  unsigned short* wkb = (unsigned short*)(ws + 3 * SZX + SZW);
  unsigned short* wvb = (unsigned short*)(ws + 3 * SZX + 2 * SZW);
  unsigned short* wob = (unsigned short*)(ws + 3 * SZX + 3 * SZW);
  unsigned short* Qb  = (unsigned short*)(ws + 3 * SZX + 4 * SZW);
  unsigned short* Kb  = (unsigned short*)(ws + 4 * SZX + 4 * SZW);
  unsigned short* Vt  = (unsigned short*)(ws + 5 * SZX + 4 * SZW);
  unsigned short* Ob  = (unsigned short*)(ws + 6 * SZX + 4 * SZW);
  unsigned long long* mb = (unsigned long long*)(ws + 7 * SZX + 4 * SZW);
  // total ws use: 7*8MB + 8MB + 1MB = 65 MB

  cvt_all_kernel<<<2048, 256, 0, stream>>>(query, key_, value, wq, wk, wv, wo, xq);
  maskbits_kernel<<<512, 256, 0, stream>>>(mask, mb);  // 131072 words

  qkv_kernel<<<dim3(8, 32, 3), 256, 0, stream>>>(xq, xk, xv, wqb, wkb, wvb,
                                                 bq, bk, bv, Qb, Kb, Vt);
  attn_kernel<<<512, 256, 0, stream>>>(Qb, Kb, Vt, mb, Ob);
  outproj_kernel<<<dim3(8, 32), 512, 0, stream>>>(Ob, wob, bo, out);
}

// Round 9
// 285.989 us; speedup vs baseline: 1.7093x; 1.0368x over previous
//
#include <hip/hip_runtime.h>
#include <hip/hip_bf16.h>
#include <stdint.h>

// Problem constants: B=2, S=2048, D=1024, H=16, dk=64
#define NB 2
#define NS 2048
#define ND 1024
#define NH 16
#define DKH 64

typedef __attribute__((ext_vector_type(8))) short bf16x8;   // 8 bf16 = 4 VGPRs
typedef __attribute__((ext_vector_type(4))) float f32x4;
typedef __attribute__((ext_vector_type(8))) unsigned short u16x8;
typedef __attribute__((ext_vector_type(4))) unsigned short u16x4;

__device__ __forceinline__ unsigned short f2bf(float x) {
  union { float f; unsigned int u; } c; c.f = x;
  unsigned int u = c.u;
  unsigned int r = (u + 0x7fffu + ((u >> 16) & 1u)) >> 16;  // round-nearest-even
  return (unsigned short)r;
}

// async global->LDS, 16B per lane; LDS dest is wave-uniform base + lane*16
#define GLOAD_LDS16(gp, lp)                                                     \
  __builtin_amdgcn_global_load_lds(                                             \
      (const __attribute__((address_space(1))) void*)(gp),                      \
      (__attribute__((address_space(3))) void*)(lp), 16, 0, 0)

// ---------------------------------------------------------------- convert ----
// fused fp32->bf16 of {query,key,value,wq,wk,wv,wo}; dsts are CONTIGUOUS in ws
__global__ __launch_bounds__(256) void cvt_all_kernel(
    const float* __restrict__ s0, const float* __restrict__ s1,
    const float* __restrict__ s2, const float* __restrict__ s3,
    const float* __restrict__ s4, const float* __restrict__ s5,
    const float* __restrict__ s6, unsigned short* __restrict__ dst) {
  const int NIN = NB * NS * ND / 8;   // 524288 groups of 8
  const int NWT = ND * ND / 8;        // 131072
  const int TOT = 3 * NIN + 4 * NWT;  // 2097152
  for (int i = blockIdx.x * blockDim.x + threadIdx.x; i < TOT;
       i += gridDim.x * blockDim.x) {
    const float* s; int off;
    if (i < NIN)            { s = s0; off = i; }
    else if (i < 2 * NIN)   { s = s1; off = i - NIN; }
    else if (i < 3 * NIN)   { s = s2; off = i - 2 * NIN; }
    else if (i < 3 * NIN + NWT)     { s = s3; off = i - 3 * NIN; }
    else if (i < 3 * NIN + 2 * NWT) { s = s4; off = i - (3 * NIN + NWT); }
    else if (i < 3 * NIN + 3 * NWT) { s = s5; off = i - (3 * NIN + 2 * NWT); }
    else                            { s = s6; off = i - (3 * NIN + 3 * NWT); }
    const float4* sp = reinterpret_cast<const float4*>(s) + (size_t)off * 2;
    float4 a = sp[0], b = sp[1];
    u16x8 o;
    o[0] = f2bf(a.x); o[1] = f2bf(a.y); o[2] = f2bf(a.z); o[3] = f2bf(a.w);
    o[4] = f2bf(b.x); o[5] = f2bf(b.y); o[6] = f2bf(b.z); o[7] = f2bf(b.w);
    reinterpret_cast<u16x8*>(dst)[i] = o;
  }
}

// mask [B,1,S,S] int32 -> bitmask, 1 bit per (q,k); word = 64 consecutive k
__global__ __launch_bounds__(256) void maskbits_kernel(const int* __restrict__ mask,
                                                       unsigned long long* __restrict__ bits) {
  int i = blockIdx.x * blockDim.x + threadIdx.x;  // one u64 word per thread
  const int4* p = reinterpret_cast<const int4*>(mask + (size_t)i * 64);
  unsigned long long w = 0;
#pragma unroll
  for (int j = 0; j < 16; j++) {
    int4 v = p[j];
    unsigned long long nib = (v.x ? 1ull : 0) | (v.y ? 2ull : 0) |
                             (v.z ? 4ull : 0) | (v.w ? 8ull : 0);
    w |= nib << (j * 4);
  }
  bits[i] = w;
}

// ------------------------------------------------------------- GEMM core ----
// C[BMxBN] = A[BMxK] * Bt[BNxK]^T ; K = 1024, BK=64, global_load_lds w=16.
// THREADS/64 waves arranged (WRN x WCN); wave tile = AM*16 x AN*16.
// SWAP=true computes D^T fragments (operands swapped) for the V-transpose path.
template <bool SWAP, int THREADS, int WCN, int AM, int AN>
__device__ __forceinline__ void gemm_core(const unsigned short* __restrict__ A,
                                          const unsigned short* __restrict__ Bt,
                                          int m0, int n0,
                                          unsigned short* As, unsigned short* Bs,
                                          f32x4 (&acc)[AM][AN]) {
  constexpr int NWAVE = THREADS / 64;
  constexpr int WRN = NWAVE / WCN;
  constexpr int BM = WRN * AM * 16;
  constexpr int BN = WCN * AN * 16;
  constexpr int JA = BM * 64 / (THREADS * 8);
  constexpr int JB = BN * 64 / (THREADS * 8);
  const int tid = threadIdx.x;
  const int w = tid >> 6;
  const int l = tid & 63;
  const int wr = w / WCN, wc = w % WCN;
  const int lr = l & 15, lg = l >> 4;

#pragma unroll
  for (int i = 0; i < AM; i++)
#pragma unroll
    for (int j = 0; j < AN; j++) acc[i][j] = (f32x4){0.f, 0.f, 0.f, 0.f};

  for (int k0 = 0; k0 < ND; k0 += 64) {
    __syncthreads();  // previous tile's compute done before overwrite
#pragma unroll
    for (int j = 0; j < JA; j++) {
      int flat = j * (THREADS * 8) + tid * 8;  // elem index in BMx64 tile
      int row = flat >> 6, col = flat & 63;
      GLOAD_LDS16(A + (size_t)(m0 + row) * ND + k0 + col,
                  As + j * (THREADS * 8) + w * 512);
    }
#pragma unroll
    for (int j = 0; j < JB; j++) {
      int flat = j * (THREADS * 8) + tid * 8;
      int row = flat >> 6, col = flat & 63;
      GLOAD_LDS16(Bt + (size_t)(n0 + row) * ND + k0 + col,
                  Bs + j * (THREADS * 8) + w * 512);
    }
    __syncthreads();  // compiler emits vmcnt(0) drain before barrier
#pragma unroll
    for (int ks = 0; ks < 2; ks++) {
      bf16x8 av[AM], bv[AN];
#pragma unroll
      for (int mi = 0; mi < AM; mi++)
        av[mi] = *reinterpret_cast<const bf16x8*>(
            As + (wr * (AM * 16) + mi * 16 + lr) * 64 + ks * 32 + lg * 8);
#pragma unroll
      for (int ni = 0; ni < AN; ni++)
        bv[ni] = *reinterpret_cast<const bf16x8*>(
            Bs + (wc * (AN * 16) + ni * 16 + lr) * 64 + ks * 32 + lg * 8);
#pragma unroll
      for (int mi = 0; mi < AM; mi++)
#pragma unroll
        for (int ni = 0; ni < AN; ni++)
          acc[mi][ni] = SWAP
              ? __builtin_amdgcn_mfma_f32_16x16x32_bf16(bv[ni], av[mi], acc[mi][ni], 0, 0, 0)
              : __builtin_amdgcn_mfma_f32_16x16x32_bf16(av[mi], bv[ni], acc[mi][ni], 0, 0, 0);
    }
  }
}

// QKV projection: z=0 Q (pre-scaled by 1/sqrt(dk)), z=1 K (store [B,H,S,dk]);
// z=2 V (store transposed [B,H,dk,S])
__global__ __launch_bounds__(256, 2) void qkv_kernel(
    const unsigned short* __restrict__ Xq, const unsigned short* __restrict__ Xk,
    const unsigned short* __restrict__ Xv, const unsigned short* __restrict__ Wq,
    const unsigned short* __restrict__ Wk, const unsigned short* __restrict__ Wv,
    const float* __restrict__ bq, const float* __restrict__ bk,
    const float* __restrict__ bv, unsigned short* __restrict__ Qo,
    unsigned short* __restrict__ Ko, unsigned short* __restrict__ Vt) {
  __shared__ __align__(16) unsigned short As[128 * 64];
  __shared__ __align__(16) unsigned short Bs[128 * 64];
  const int z = blockIdx.z;
  const unsigned short* X = (z == 0) ? Xq : (z == 1) ? Xk : Xv;
  const unsigned short* W = (z == 0) ? Wq : (z == 1) ? Wk : Wv;
  const float* bias = (z == 0) ? bq : (z == 1) ? bk : bv;
  const int m0 = blockIdx.y * 128, n0 = blockIdx.x * 128;
  const int tid = threadIdx.x;
  const int w = tid >> 6, l = tid & 63;
  const int wr = w >> 1, wc = w & 1, lr = l & 15, lg = l >> 4;
  f32x4 acc[4][4];

  if (z < 2) {
    gemm_core<false, 256, 2, 4, 4>(X, W, m0, n0, As, Bs, acc);
    unsigned short* O = (z == 0) ? Qo : Ko;
    const float scl = (z == 0) ? 0.125f : 1.0f;  // fold 1/sqrt(64) into Q
#pragma unroll
    for (int mi = 0; mi < 4; mi++)
#pragma unroll
      for (int ni = 0; ni < 4; ni++)
#pragma unroll
        for (int r = 0; r < 4; r++) {
          int mrow = m0 + wr * 64 + mi * 16 + lg * 4 + r;   // b*S+s
          int ncol = n0 + wc * 64 + ni * 16 + lr;           // h*dk+d
          float y = (acc[mi][ni][r] + bias[ncol]) * scl;
          int bb = mrow >> 11, s = mrow & 2047, hh = ncol >> 6, d = ncol & 63;
          O[(((size_t)(bb * NH + hh)) * NS + s) * DKH + d] = f2bf(y);
        }
  } else {
    gemm_core<true, 256, 2, 4, 4>(X, W, m0, n0, As, Bs, acc);  // D^T fragments
#pragma unroll
    for (int mi = 0; mi < 4; mi++)
#pragma unroll
      for (int ni = 0; ni < 4; ni++)
#pragma unroll
        for (int r = 0; r < 4; r++) {
          int ncol = n0 + wc * 64 + ni * 16 + lg * 4 + r;   // output feature
          int mrow = m0 + wr * 64 + mi * 16 + lr;           // b*S+s (lane-consec)
          float y = acc[mi][ni][r] + bias[ncol];
          int bb = mrow >> 11, s = mrow & 2047, hh = ncol >> 6, d = ncol & 63;
          Vt[(((size_t)(bb * NH + hh)) * DKH + d) * NS + s] = f2bf(y);
        }
  }
}

// output projection: out = O @ wo^T + bo, fp32 out. 8 waves (2x4), wave 64x32.
__global__ __launch_bounds__(512, 2) void outproj_kernel(
    const unsigned short* __restrict__ Oin, const unsigned short* __restrict__ Wo,
    const float* __restrict__ bo, float* __restrict__ out) {
  __shared__ __align__(16) unsigned short As[128 * 64];
  __shared__ __align__(16) unsigned short Bs[128 * 64];
  const int m0 = blockIdx.y * 128, n0 = blockIdx.x * 128;
  const int tid = threadIdx.x;
  const int w = tid >> 6, l = tid & 63;
  const int wr = w >> 2, wc = w & 3, lr = l & 15, lg = l >> 4;
  f32x4 acc[4][2];
  gemm_core<false, 512, 4, 4, 2>(Oin, Wo, m0, n0, As, Bs, acc);
#pragma unroll
  for (int mi = 0; mi < 4; mi++)
#pragma unroll
    for (int ni = 0; ni < 2; ni++)
#pragma unroll
      for (int r = 0; r < 4; r++) {
        int mrow = m0 + wr * 64 + mi * 16 + lg * 4 + r;
        int ncol = n0 + wc * 32 + ni * 16 + lr;
        out[(size_t)mrow * ND + ncol] = acc[mi][ni][r] + bo[ncol];
      }
}

// ----------------------------------------------------------- attention ------
// Block = (b, h, 128 q-rows); 4 waves x 32 q-rows (2 m-slots of 16).
// K and V^T tiles (64x64 bf16, 8KB each) staged cooperatively in LDS with
// XOR swizzle (chunk ^= row&7), double-buffered; one barrier per K-tile.
// Swapped QK^T (mfma(K,Q)): lane owns one q-row per m-slot -> in-register
// softmax (R7-verified). R8: VALU thinning — cvt_pk bf16 pack, defer-max
// rescale skip (THR=8), fused exp2.
__global__ __launch_bounds__(256, 3) void attn_kernel(
    const unsigned short* __restrict__ Qg, const unsigned short* __restrict__ Kg,
    const unsigned short* __restrict__ Vtg,
    const unsigned long long* __restrict__ mbits,
    unsigned short* __restrict__ Og) {
  __shared__ __align__(16) unsigned short Ks[2][64 * 64];
  __shared__ __align__(16) unsigned short Vs[2][64 * 64];
  const int tid = threadIdx.x;
  const int w = tid >> 6, l = tid & 63;
  const int lr = l & 15, lg = l >> 4;
  // head-major decode: head h always lands on XCD h%8 (blockIdx RR over XCDs)
  const int lin = blockIdx.x;          // 512 blocks
  const int h = lin & 15;
  const int rest = lin >> 4;           // [0,32)
  const int qblk = rest & 15;          // 16 q-blocks of 128 rows
  const int b = rest >> 4;
  const int qbase = qblk * 128 + w * 32;

  const unsigned short* Qh = Qg + ((size_t)(b * NH + h)) * NS * DKH;
  const unsigned short* Kh = Kg + ((size_t)(b * NH + h)) * NS * DKH;
  const unsigned short* Vth = Vtg + ((size_t)(b * NH + h)) * DKH * NS;
  const unsigned long long* mrowp[2] = {
      mbits + (size_t)(b * NS + qbase + lr) * (NS / 64),
      mbits + (size_t)(b * NS + qbase + 16 + lr) * (NS / 64)};

  // Q fragments, 2 m-slots (Q pre-scaled by 1/sqrt(dk) in qkv)
  bf16x8 aQ[2][2];
#pragma unroll
  for (int m = 0; m < 2; m++)
#pragma unroll
    for (int ks = 0; ks < 2; ks++)
      aQ[m][ks] = *reinterpret_cast<const bf16x8*>(
          Qh + (size_t)(qbase + m * 16 + lr) * DKH + ks * 32 + lg * 8);

  f32x4 accT[2][4];
#pragma unroll
  for (int m = 0; m < 2; m++)
#pragma unroll
    for (int nd = 0; nd < 4; nd++) accT[m][nd] = (f32x4){0.f, 0.f, 0.f, 0.f};
  float mrun[2] = {-3.0e38f, -3.0e38f}, lrun[2] = {0.f, 0.f};

  // cooperative staging: 8KB tile = 512 chunks of 16B; 256 threads x 2 insts.
  // pre-swizzled SOURCE (chunk-in-row ^= row&7) + linear LDS dest + swizzled
  // ds_read => net identity (rule: both-sides-or-neither).
#define STAGE_TILES(bufi, kk0)                                                  \
  {                                                                             \
    _Pragma("unroll") for (int j = 0; j < 2; j++) {                             \
      int c = j * 256 + tid;                                                    \
      int row = c >> 3;                                                         \
      int cr = (c & 7) ^ (row & 7);                                             \
      GLOAD_LDS16(Kh + (size_t)((kk0) + row) * DKH + cr * 8,                    \
                  &Ks[bufi][(size_t)(j * 256 + w * 64) * 8]);                   \
    }                                                                           \
    _Pragma("unroll") for (int j = 0; j < 2; j++) {                             \
      int c = j * 256 + tid;                                                    \
      int row = c >> 3;                                                         \
      int cr = (c & 7) ^ (row & 7);                                             \
      GLOAD_LDS16(Vth + (size_t)row * NS + (kk0) + cr * 8,                      \
                  &Vs[bufi][(size_t)(j * 256 + w * 64) * 8]);                   \
    }                                                                           \
  }

  STAGE_TILES(0, 0)
  __syncthreads();  // compiler drains vmcnt before barrier
  int buf = 0;
  const float L2E = 1.4426950408889634f;

  for (int t = 0; t < NS / 64; t++) {
    const int kk0 = t * 64;
    if (t < NS / 64 - 1) STAGE_TILES(buf ^ 1, kk0 + 64)
    unsigned long long w64m[2] = {mrowp[0][t], mrowp[1][t]};
    // K fragments from LDS (shared across both m-slots)
    bf16x8 kb[4][2];
#pragma unroll
    for (int n = 0; n < 4; n++)
#pragma unroll
      for (int ks = 0; ks < 2; ks++)
        kb[n][ks] = *reinterpret_cast<const bf16x8*>(
            &Ks[buf][(size_t)(n * 16 + lr) * 64 +
                     (size_t)(((ks * 4 + lg) ^ (lr & 7)) * 8)]);
    // QK^T: sT[m][n][r] = S[qbase+m*16+lr][kk0 + n*16 + lg*4 + r]
    f32x4 sT[2][4];
#pragma unroll
    for (int m = 0; m < 2; m++)
#pragma unroll
      for (int n = 0; n < 4; n++) sT[m][n] = (f32x4){0.f, 0.f, 0.f, 0.f};
    __builtin_amdgcn_s_setprio(1);
#pragma unroll
    for (int ks = 0; ks < 2; ks++)
#pragma unroll
      for (int m = 0; m < 2; m++)
#pragma unroll
        for (int n = 0; n < 4; n++)
          sT[m][n] = __builtin_amdgcn_mfma_f32_16x16x32_bf16(kb[n][ks], aQ[m][ks],
                                                             sT[m][n], 0, 0, 0);
    __builtin_amdgcn_s_setprio(0);
    // V fragments (LDS reads issued early; consumed after softmax)
    bf16x8 vb[4][2];
#pragma unroll
    for (int nd = 0; nd < 4; nd++)
#pragma unroll
      for (int ks = 0; ks < 2; ks++)
        vb[nd][ks] = *reinterpret_cast<const bf16x8*>(
            &Vs[buf][(size_t)(nd * 16 + lr) * 64 +
                     (size_t)(((ks * 4 + lg) ^ (lr & 7)) * 8)]);

#pragma unroll
    for (int m = 0; m < 2; m++) {
      unsigned long long w64 = w64m[m];
      if (w64 != ~0ull) {
        unsigned long long wsh = w64 >> (lg * 4);
#pragma unroll
        for (int n = 0; n < 4; n++)
#pragma unroll
          for (int r = 0; r < 4; r++)
            if (!((wsh >> (n * 16 + r)) & 1ull)) sT[m][n][r] = -1e9f;
      }
      // online softmax, per-lane stats (one q-row per lane per m-slot)
      float m0 = fmaxf(fmaxf(sT[m][0][0], sT[m][0][1]), fmaxf(sT[m][0][2], sT[m][0][3]));
      float m1 = fmaxf(fmaxf(sT[m][1][0], sT[m][1][1]), fmaxf(sT[m][1][2], sT[m][1][3]));
      float m2 = fmaxf(fmaxf(sT[m][2][0], sT[m][2][1]), fmaxf(sT[m][2][2], sT[m][2][3]));
      float m3 = fmaxf(fmaxf(sT[m][3][0], sT[m][3][1]), fmaxf(sT[m][3][2], sT[m][3][3]));
      float mx = fmaxf(fmaxf(m0, m1), fmaxf(m2, m3));
      mx = fmaxf(mx, __shfl_xor(mx, 16));
      mx = fmaxf(mx, __shfl_xor(mx, 32));
      // defer-max (T13): skip rescale when tile max is within THR of running
      // max — P then bounded by e^8, harmless in f32/bf16. First tile never
      // skips (mrun = -3e38).
      float nm;
      if (__all(mx <= mrun[m] + 8.0f)) {
        nm = mrun[m];
      } else {
        nm = fmaxf(mrun[m], mx);
        float corr = __expf(mrun[m] - nm);
        mrun[m] = nm;
        lrun[m] *= corr;
#pragma unroll
        for (int nd = 0; nd < 4; nd++) accT[m][nd] *= corr;
      }
      // p = exp2(s*log2e - nm*log2e): 1 fma + 1 exp per element
      const float nmL = nm * L2E;
      float p[4][4];
      float psum = 0.f;
#pragma unroll
      for (int n = 0; n < 4; n++) {
#pragma unroll
        for (int r = 0; r < 4; r++)
          p[n][r] = __builtin_amdgcn_exp2f(__builtin_fmaf(sT[m][n][r], L2E, -nmL));
        psum += (p[n][0] + p[n][1]) + (p[n][2] + p[n][3]);
      }
      psum += __shfl_xor(psum, 16);
      psum += __shfl_xor(psum, 32);
      lrun[m] += psum;
      // pack P pairs to bf16 words via HW cvt: w32[n][hh] = (p[2hh], p[2hh+1])
      unsigned int w32[4][2];
#pragma unroll
      for (int n = 0; n < 4; n++)
#pragma unroll
        for (int hh = 0; hh < 2; hh++)
          asm("v_cvt_pk_bf16_f32 %0, %1, %2"
              : "=v"(w32[n][hh])
              : "v"(p[n][2 * hh]), "v"(p[n][2 * hh + 1]));
      // redistribute to PV B-operand (verified r5): lane gets P[q=lr][k-slice]
      const int src0 = lr + ((lg & 1) << 5);
      const bool hi = (lg & 2) != 0;
      bf16x8 pa[2];
#pragma unroll
      for (int ks = 0; ks < 2; ks++) {
        unsigned a0 = __shfl((int)w32[2 * ks][0], src0, 64);
        unsigned a1 = __shfl((int)w32[2 * ks][1], src0, 64);
        unsigned a2 = __shfl((int)w32[2 * ks][0], src0 + 16, 64);
        unsigned a3 = __shfl((int)w32[2 * ks][1], src0 + 16, 64);
        unsigned b0 = __shfl((int)w32[2 * ks + 1][0], src0, 64);
        unsigned b1 = __shfl((int)w32[2 * ks + 1][1], src0, 64);
        unsigned b2 = __shfl((int)w32[2 * ks + 1][0], src0 + 16, 64);
        unsigned b3 = __shfl((int)w32[2 * ks + 1][1], src0 + 16, 64);
        union { unsigned int u[4]; bf16x8 v; } cv;
        cv.u[0] = hi ? b0 : a0;
        cv.u[1] = hi ? b1 : a1;
        cv.u[2] = hi ? b2 : a2;
        cv.u[3] = hi ? b3 : a3;
        pa[ks] = cv.v;
      }
      // PV: accT[m][nd][r] = O[q][d = nd*16 + lg*4 + r]
      __builtin_amdgcn_s_setprio(1);
#pragma unroll
      for (int ks = 0; ks < 2; ks++)
#pragma unroll
        for (int nd = 0; nd < 4; nd++)
          accT[m][nd] = __builtin_amdgcn_mfma_f32_16x16x32_bf16(vb[nd][ks], pa[ks],
                                                                accT[m][nd], 0, 0, 0);
      __builtin_amdgcn_s_setprio(0);
    }
    __syncthreads();  // staging of t+1 drained; all waves done reading buf
    buf ^= 1;
  }
#undef STAGE_TILES

  // epilogue: O[qa][h*64 + nd*16 + lg*4 + r]
#pragma unroll
  for (int m = 0; m < 2; m++) {
    float inv = 1.0f / lrun[m];
    int qa = qbase + m * 16 + lr;
#pragma unroll
    for (int nd = 0; nd < 4; nd++) {
      u16x4 o;
#pragma unroll
      for (int r = 0; r < 4; r++) o[r] = f2bf(accT[m][nd][r] * inv);
      *reinterpret_cast<u16x4*>(
          Og + ((size_t)(b * NS + qa)) * ND + h * DKH + nd * 16 + lg * 4) = o;
    }
  }
}

// ---------------------------------------------------------------- launch ----
extern "C" void kernel_launch(void* const* d_in, const int* in_sizes, int n_in,
                              void* d_out, int out_size, void* d_ws, size_t ws_size,
                              hipStream_t stream) {
  (void)in_sizes; (void)n_in; (void)out_size; (void)ws_size;
  const float* query = (const float*)d_in[0];
  const float* key_  = (const float*)d_in[1];
  const float* value = (const float*)d_in[2];
  const int*   mask  = (const int*)d_in[3];
  const float* wq = (const float*)d_in[4];
  const float* bq = (const float*)d_in[5];
  const float* wk = (const float*)d_in[6];
  const float* bk = (const float*)d_in[7];
  const float* wv = (const float*)d_in[8];
  const float* bv = (const float*)d_in[9];
  const float* wo = (const float*)d_in[10];
  const float* bo = (const float*)d_in[11];
  float* out = (float*)d_out;

  char* ws = (char*)d_ws;
  const size_t SZX = (size_t)NB * NS * ND * 2;  // 8 MB (bf16 [4096,1024])
  const size_t SZW = (size_t)ND * ND * 2;       // 2 MB
  unsigned short* xq  = (unsigned short*)(ws);
  unsigned short* xk  = (unsigned short*)(ws + SZX);
  unsigned short* xv  = (unsigned short*)(ws + 2 * SZX);
  unsigned short* wqb = (unsigned short*)(ws + 3 * SZX);
  unsigned short* wkb = (unsigned short*)(ws + 3 * SZX + SZW);
  unsigned short* wvb = (unsigned short*)(ws + 3 * SZX + 2 * SZW);
  unsigned short* wob = (unsigned short*)(ws + 3 * SZX + 3 * SZW);
  unsigned short* Qb  = (unsigned short*)(ws + 3 * SZX + 4 * SZW);
  unsigned short* Kb  = (unsigned short*)(ws + 4 * SZX + 4 * SZW);
  unsigned short* Vt  = (unsigned short*)(ws + 5 * SZX + 4 * SZW);
  unsigned short* Ob  = (unsigned short*)(ws + 6 * SZX + 4 * SZW);
  unsigned long long* mb = (unsigned long long*)(ws + 7 * SZX + 4 * SZW);
  // total ws use: 7*8MB + 8MB + 1MB = 65 MB

  cvt_all_kernel<<<2048, 256, 0, stream>>>(query, key_, value, wq, wk, wv, wo, xq);
  maskbits_kernel<<<512, 256, 0, stream>>>(mask, mb);  // 131072 words

  qkv_kernel<<<dim3(8, 32, 3), 256, 0, stream>>>(xq, xk, xv, wqb, wkb, wvb,
                                                 bq, bk, bv, Qb, Kb, Vt);
  attn_kernel<<<512, 256, 0, stream>>>(Qb, Kb, Vt, mb, Ob);
  outproj_kernel<<<dim3(8, 32), 512, 0, stream>>>(Ob, wob, bo, out);
}

// Round 10
// 282.095 us; speedup vs baseline: 1.7329x; 1.0138x over previous
//
#include <hip/hip_runtime.h>
#include <hip/hip_bf16.h>
#include <stdint.h>

// Problem constants: B=2, S=2048, D=1024, H=16, dk=64
#define NB 2
#define NS 2048
#define ND 1024
#define NH 16
#define DKH 64

typedef __attribute__((ext_vector_type(8))) short bf16x8;   // 8 bf16 = 4 VGPRs
typedef __attribute__((ext_vector_type(4))) float f32x4;
typedef __attribute__((ext_vector_type(8))) unsigned short u16x8;
typedef __attribute__((ext_vector_type(4))) unsigned short u16x4;

__device__ __forceinline__ unsigned short f2bf(float x) {
  union { float f; unsigned int u; } c; c.f = x;
  unsigned int u = c.u;
  unsigned int r = (u + 0x7fffu + ((u >> 16) & 1u)) >> 16;  // round-nearest-even
  return (unsigned short)r;
}

// async global->LDS, 16B per lane; LDS dest is wave-uniform base + lane*16
#define GLOAD_LDS16(gp, lp)                                                     \
  __builtin_amdgcn_global_load_lds(                                             \
      (const __attribute__((address_space(1))) void*)(gp),                      \
      (__attribute__((address_space(3))) void*)(lp), 16, 0, 0)

// ------------------------------------------------------------------ prep ----
// blocks [0,2048): fused fp32->bf16 of {query,key,value,wq,wk,wv,wo} into
// contiguous ws. blocks [2048,2560): mask [B,1,S,S] int32 -> bitmask.
__global__ __launch_bounds__(256) void prep_kernel(
    const float* __restrict__ s0, const float* __restrict__ s1,
    const float* __restrict__ s2, const float* __restrict__ s3,
    const float* __restrict__ s4, const float* __restrict__ s5,
    const float* __restrict__ s6, unsigned short* __restrict__ dst,
    const int* __restrict__ mask, unsigned long long* __restrict__ bits) {
  const int NIN = NB * NS * ND / 8;   // 524288 groups of 8
  const int NWT = ND * ND / 8;        // 131072
  const int TOT = 3 * NIN + 4 * NWT;  // 2097152
  if (blockIdx.x < 2048) {
    for (int i = blockIdx.x * blockDim.x + threadIdx.x; i < TOT;
         i += 2048 * 256) {
      const float* s; int off;
      if (i < NIN)            { s = s0; off = i; }
      else if (i < 2 * NIN)   { s = s1; off = i - NIN; }
      else if (i < 3 * NIN)   { s = s2; off = i - 2 * NIN; }
      else if (i < 3 * NIN + NWT)     { s = s3; off = i - 3 * NIN; }
      else if (i < 3 * NIN + 2 * NWT) { s = s4; off = i - (3 * NIN + NWT); }
      else if (i < 3 * NIN + 3 * NWT) { s = s5; off = i - (3 * NIN + 2 * NWT); }
      else                            { s = s6; off = i - (3 * NIN + 3 * NWT); }
      const float4* sp = reinterpret_cast<const float4*>(s) + (size_t)off * 2;
      float4 a = sp[0], b = sp[1];
      u16x8 o;
      o[0] = f2bf(a.x); o[1] = f2bf(a.y); o[2] = f2bf(a.z); o[3] = f2bf(a.w);
      o[4] = f2bf(b.x); o[5] = f2bf(b.y); o[6] = f2bf(b.z); o[7] = f2bf(b.w);
      reinterpret_cast<u16x8*>(dst)[i] = o;
    }
  } else {
    int i = (blockIdx.x - 2048) * blockDim.x + threadIdx.x;  // one u64/thread
    const int4* p = reinterpret_cast<const int4*>(mask + (size_t)i * 64);
    unsigned long long w = 0;
#pragma unroll
    for (int j = 0; j < 16; j++) {
      int4 v = p[j];
      unsigned long long nib = (v.x ? 1ull : 0) | (v.y ? 2ull : 0) |
                               (v.z ? 4ull : 0) | (v.w ? 8ull : 0);
      w |= nib << (j * 4);
    }
    bits[i] = w;
  }
}

// ------------------------------------------------------------- GEMM core ----
// C[BMxBN] = A[BMxK] * Bt[BNxK]^T ; K = 1024, BK=64, global_load_lds w=16.
// THREADS/64 waves arranged (WRN x WCN); wave tile = AM*16 x AN*16.
// SWAP=true computes D^T fragments (operands swapped) for the V-transpose path.
template <bool SWAP, int THREADS, int WCN, int AM, int AN>
__device__ __forceinline__ void gemm_core(const unsigned short* __restrict__ A,
                                          const unsigned short* __restrict__ Bt,
                                          int m0, int n0,
                                          unsigned short* As, unsigned short* Bs,
                                          f32x4 (&acc)[AM][AN]) {
  constexpr int NWAVE = THREADS / 64;
  constexpr int WRN = NWAVE / WCN;
  constexpr int BM = WRN * AM * 16;
  constexpr int BN = WCN * AN * 16;
  constexpr int JA = BM * 64 / (THREADS * 8);
  constexpr int JB = BN * 64 / (THREADS * 8);
  const int tid = threadIdx.x;
  const int w = tid >> 6;
  const int l = tid & 63;
  const int wr = w / WCN, wc = w % WCN;
  const int lr = l & 15, lg = l >> 4;

#pragma unroll
  for (int i = 0; i < AM; i++)
#pragma unroll
    for (int j = 0; j < AN; j++) acc[i][j] = (f32x4){0.f, 0.f, 0.f, 0.f};

  for (int k0 = 0; k0 < ND; k0 += 64) {
    __syncthreads();  // previous tile's compute done before overwrite
#pragma unroll
    for (int j = 0; j < JA; j++) {
      int flat = j * (THREADS * 8) + tid * 8;  // elem index in BMx64 tile
      int row = flat >> 6, col = flat & 63;
      GLOAD_LDS16(A + (size_t)(m0 + row) * ND + k0 + col,
                  As + j * (THREADS * 8) + w * 512);
    }
#pragma unroll
    for (int j = 0; j < JB; j++) {
      int flat = j * (THREADS * 8) + tid * 8;
      int row = flat >> 6, col = flat & 63;
      GLOAD_LDS16(Bt + (size_t)(n0 + row) * ND + k0 + col,
                  Bs + j * (THREADS * 8) + w * 512);
    }
    __syncthreads();  // compiler emits vmcnt(0) drain before barrier
#pragma unroll
    for (int ks = 0; ks < 2; ks++) {
      bf16x8 av[AM], bv[AN];
#pragma unroll
      for (int mi = 0; mi < AM; mi++)
        av[mi] = *reinterpret_cast<const bf16x8*>(
            As + (wr * (AM * 16) + mi * 16 + lr) * 64 + ks * 32 + lg * 8);
#pragma unroll
      for (int ni = 0; ni < AN; ni++)
        bv[ni] = *reinterpret_cast<const bf16x8*>(
            Bs + (wc * (AN * 16) + ni * 16 + lr) * 64 + ks * 32 + lg * 8);
#pragma unroll
      for (int mi = 0; mi < AM; mi++)
#pragma unroll
        for (int ni = 0; ni < AN; ni++)
          acc[mi][ni] = SWAP
              ? __builtin_amdgcn_mfma_f32_16x16x32_bf16(bv[ni], av[mi], acc[mi][ni], 0, 0, 0)
              : __builtin_amdgcn_mfma_f32_16x16x32_bf16(av[mi], bv[ni], acc[mi][ni], 0, 0, 0);
    }
  }
}

// QKV projection: z=0 Q (pre-scaled by 1/sqrt(dk)), z=1 K (store [B,H,S,dk]);
// z=2 V (store transposed [B,H,dk,S])
__global__ __launch_bounds__(256, 2) void qkv_kernel(
    const unsigned short* __restrict__ Xq, const unsigned short* __restrict__ Xk,
    const unsigned short* __restrict__ Xv, const unsigned short* __restrict__ Wq,
    const unsigned short* __restrict__ Wk, const unsigned short* __restrict__ Wv,
    const float* __restrict__ bq, const float* __restrict__ bk,
    const float* __restrict__ bv, unsigned short* __restrict__ Qo,
    unsigned short* __restrict__ Ko, unsigned short* __restrict__ Vt) {
  __shared__ __align__(16) unsigned short As[128 * 64];
  __shared__ __align__(16) unsigned short Bs[128 * 64];
  const int z = blockIdx.z;
  const unsigned short* X = (z == 0) ? Xq : (z == 1) ? Xk : Xv;
  const unsigned short* W = (z == 0) ? Wq : (z == 1) ? Wk : Wv;
  const float* bias = (z == 0) ? bq : (z == 1) ? bk : bv;
  const int m0 = blockIdx.y * 128, n0 = blockIdx.x * 128;
  const int tid = threadIdx.x;
  const int w = tid >> 6, l = tid & 63;
  const int wr = w >> 1, wc = w & 1, lr = l & 15, lg = l >> 4;
  f32x4 acc[4][4];

  if (z < 2) {
    gemm_core<false, 256, 2, 4, 4>(X, W, m0, n0, As, Bs, acc);
    unsigned short* O = (z == 0) ? Qo : Ko;
    const float scl = (z == 0) ? 0.125f : 1.0f;  // fold 1/sqrt(64) into Q
#pragma unroll
    for (int mi = 0; mi < 4; mi++)
#pragma unroll
      for (int ni = 0; ni < 4; ni++)
#pragma unroll
        for (int r = 0; r < 4; r++) {
          int mrow = m0 + wr * 64 + mi * 16 + lg * 4 + r;   // b*S+s
          int ncol = n0 + wc * 64 + ni * 16 + lr;           // h*dk+d
          float y = (acc[mi][ni][r] + bias[ncol]) * scl;
          int bb = mrow >> 11, s = mrow & 2047, hh = ncol >> 6, d = ncol & 63;
          O[(((size_t)(bb * NH + hh)) * NS + s) * DKH + d] = f2bf(y);
        }
  } else {
    gemm_core<true, 256, 2, 4, 4>(X, W, m0, n0, As, Bs, acc);  // D^T fragments
#pragma unroll
    for (int mi = 0; mi < 4; mi++)
#pragma unroll
      for (int ni = 0; ni < 4; ni++)
#pragma unroll
        for (int r = 0; r < 4; r++) {
          int ncol = n0 + wc * 64 + ni * 16 + lg * 4 + r;   // output feature
          int mrow = m0 + wr * 64 + mi * 16 + lr;           // b*S+s (lane-consec)
          float y = acc[mi][ni][r] + bias[ncol];
          int bb = mrow >> 11, s = mrow & 2047, hh = ncol >> 6, d = ncol & 63;
          Vt[(((size_t)(bb * NH + hh)) * DKH + d) * NS + s] = f2bf(y);
        }
  }
}

// output projection: out = O @ wo^T + bo, fp32 out. 8 waves (2x4), wave 64x32.
__global__ __launch_bounds__(512, 2) void outproj_kernel(
    const unsigned short* __restrict__ Oin, const unsigned short* __restrict__ Wo,
    const float* __restrict__ bo, float* __restrict__ out) {
  __shared__ __align__(16) unsigned short As[128 * 64];
  __shared__ __align__(16) unsigned short Bs[128 * 64];
  const int m0 = blockIdx.y * 128, n0 = blockIdx.x * 128;
  const int tid = threadIdx.x;
  const int w = tid >> 6, l = tid & 63;
  const int wr = w >> 2, wc = w & 3, lr = l & 15, lg = l >> 4;
  f32x4 acc[4][2];
  gemm_core<false, 512, 4, 4, 2>(Oin, Wo, m0, n0, As, Bs, acc);
#pragma unroll
  for (int mi = 0; mi < 4; mi++)
#pragma unroll
    for (int ni = 0; ni < 2; ni++)
#pragma unroll
      for (int r = 0; r < 4; r++) {
        int mrow = m0 + wr * 64 + mi * 16 + lg * 4 + r;
        int ncol = n0 + wc * 32 + ni * 16 + lr;
        out[(size_t)mrow * ND + ncol] = acc[mi][ni][r] + bo[ncol];
      }
}

// ----------------------------------------------------------- attention ------
// R10: Block = (b, h, 128 q-rows); 8 waves x 16 q-rows (512 threads).
// K and V^T tiles (64x64 bf16, 8KB each) staged cooperatively in LDS with
// XOR swizzle (chunk ^= row&7), double-buffered; one barrier per K-tile.
// Staging per block unchanged vs R9 (same dedup), but 16 waves/CU resident.
// Swapped QK^T (mfma(K,Q)): lane owns one q-row -> in-register softmax;
// defer-max (THR=8), fused exp2, cvt_pk pack (R9-verified); P redistributed
// to PV B-operand via 16 shuffles (R5-verified).
__global__ __launch_bounds__(512, 2) void attn_kernel(
    const unsigned short* __restrict__ Qg, const unsigned short* __restrict__ Kg,
    const unsigned short* __restrict__ Vtg,
    const unsigned long long* __restrict__ mbits,
    unsigned short* __restrict__ Og) {
  __shared__ __align__(16) unsigned short Ks[2][64 * 64];
  __shared__ __align__(16) unsigned short Vs[2][64 * 64];
  const int tid = threadIdx.x;
  const int w = tid >> 6, l = tid & 63;  // 8 waves
  const int lr = l & 15, lg = l >> 4;
  // head-major decode: head h always lands on XCD h%8 (blockIdx RR over XCDs)
  const int lin = blockIdx.x;          // 512 blocks
  const int h = lin & 15;
  const int rest = lin >> 4;           // [0,32)
  const int qblk = rest & 15;          // 16 q-blocks of 128 rows
  const int b = rest >> 4;
  const int qbase = qblk * 128 + w * 16;
  const int qa = qbase + lr;           // this lane's q-row

  const unsigned short* Qh = Qg + ((size_t)(b * NH + h)) * NS * DKH;
  const unsigned short* Kh = Kg + ((size_t)(b * NH + h)) * NS * DKH;
  const unsigned short* Vth = Vtg + ((size_t)(b * NH + h)) * DKH * NS;
  const unsigned long long* mrow = mbits + (size_t)(b * NS + qa) * (NS / 64);

  // Q fragments (Q pre-scaled by 1/sqrt(dk) in qkv)
  bf16x8 aQ[2];
#pragma unroll
  for (int ks = 0; ks < 2; ks++)
    aQ[ks] = *reinterpret_cast<const bf16x8*>(
        Qh + (size_t)qa * DKH + ks * 32 + lg * 8);

  f32x4 accT[4];
#pragma unroll
  for (int nd = 0; nd < 4; nd++) accT[nd] = (f32x4){0.f, 0.f, 0.f, 0.f};
  float mrun = -3.0e38f, lrun = 0.f;

  // cooperative staging: 8KB tile = 512 chunks of 16B; 512 threads x 1 inst.
  // pre-swizzled SOURCE (chunk-in-row ^= row&7) + linear LDS dest + swizzled
  // ds_read => net identity (rule: both-sides-or-neither).
#define STAGE_TILES(bufi, kk0)                                                  \
  {                                                                             \
    int row = tid >> 3;                                                         \
    int cr = (tid & 7) ^ (row & 7);                                             \
    GLOAD_LDS16(Kh + (size_t)((kk0) + row) * DKH + cr * 8,                      \
                &Ks[bufi][(size_t)w * 512]);                                    \
    GLOAD_LDS16(Vth + (size_t)row * NS + (kk0) + cr * 8,                        \
                &Vs[bufi][(size_t)w * 512]);                                    \
  }

  STAGE_TILES(0, 0)
  __syncthreads();  // compiler drains vmcnt before barrier
  int buf = 0;
  const float L2E = 1.4426950408889634f;

  for (int t = 0; t < NS / 64; t++) {
    const int kk0 = t * 64;
    if (t < NS / 64 - 1) STAGE_TILES(buf ^ 1, kk0 + 64)
    unsigned long long w64 = mrow[t];
    // K fragments from LDS
    bf16x8 kb[4][2];
#pragma unroll
    for (int n = 0; n < 4; n++)
#pragma unroll
      for (int ks = 0; ks < 2; ks++)
        kb[n][ks] = *reinterpret_cast<const bf16x8*>(
            &Ks[buf][(size_t)(n * 16 + lr) * 64 +
                     (size_t)(((ks * 4 + lg) ^ (lr & 7)) * 8)]);
    // QK^T: sT[n][r] = S[qa][kk0 + n*16 + lg*4 + r]
    f32x4 sT[4];
#pragma unroll
    for (int n = 0; n < 4; n++) sT[n] = (f32x4){0.f, 0.f, 0.f, 0.f};
    __builtin_amdgcn_s_setprio(1);
#pragma unroll
    for (int ks = 0; ks < 2; ks++)
#pragma unroll
      for (int n = 0; n < 4; n++)
        sT[n] = __builtin_amdgcn_mfma_f32_16x16x32_bf16(kb[n][ks], aQ[ks],
                                                        sT[n], 0, 0, 0);
    __builtin_amdgcn_s_setprio(0);
    // V fragments (LDS reads issued early; consumed after softmax)
    bf16x8 vb[4][2];
#pragma unroll
    for (int nd = 0; nd < 4; nd++)
#pragma unroll
      for (int ks = 0; ks < 2; ks++)
        vb[nd][ks] = *reinterpret_cast<const bf16x8*>(
            &Vs[buf][(size_t)(nd * 16 + lr) * 64 +
                     (size_t)(((ks * 4 + lg) ^ (lr & 7)) * 8)]);

    if (w64 != ~0ull) {
      unsigned long long wsh = w64 >> (lg * 4);
#pragma unroll
      for (int n = 0; n < 4; n++)
#pragma unroll
        for (int r = 0; r < 4; r++)
          if (!((wsh >> (n * 16 + r)) & 1ull)) sT[n][r] = -1e9f;
    }
    // online softmax, per-lane stats (one q-row per lane)
    float m0 = fmaxf(fmaxf(sT[0][0], sT[0][1]), fmaxf(sT[0][2], sT[0][3]));
    float m1 = fmaxf(fmaxf(sT[1][0], sT[1][1]), fmaxf(sT[1][2], sT[1][3]));
    float m2 = fmaxf(fmaxf(sT[2][0], sT[2][1]), fmaxf(sT[2][2], sT[2][3]));
    float m3 = fmaxf(fmaxf(sT[3][0], sT[3][1]), fmaxf(sT[3][2], sT[3][3]));
    float mx = fmaxf(fmaxf(m0, m1), fmaxf(m2, m3));
    mx = fmaxf(mx, __shfl_xor(mx, 16));
    mx = fmaxf(mx, __shfl_xor(mx, 32));
    // defer-max (T13): skip rescale when tile max within THR of running max
    float nm;
    if (__all(mx <= mrun + 8.0f)) {
      nm = mrun;
    } else {
      nm = fmaxf(mrun, mx);
      float corr = __expf(mrun - nm);
      mrun = nm;
      lrun *= corr;
#pragma unroll
      for (int nd = 0; nd < 4; nd++) accT[nd] *= corr;
    }
    // p = exp2(s*log2e - nm*log2e): 1 fma + 1 exp per element
    const float nmL = nm * L2E;
    float p[4][4];
    float psum = 0.f;
#pragma unroll
    for (int n = 0; n < 4; n++) {
#pragma unroll
      for (int r = 0; r < 4; r++)
        p[n][r] = __builtin_amdgcn_exp2f(__builtin_fmaf(sT[n][r], L2E, -nmL));
      psum += (p[n][0] + p[n][1]) + (p[n][2] + p[n][3]);
    }
    psum += __shfl_xor(psum, 16);
    psum += __shfl_xor(psum, 32);
    lrun += psum;
    // pack P pairs to bf16 words via HW cvt: w32[n][hh] = (p[2hh], p[2hh+1])
    unsigned int w32[4][2];
#pragma unroll
    for (int n = 0; n < 4; n++)
#pragma unroll
      for (int hh = 0; hh < 2; hh++)
        asm("v_cvt_pk_bf16_f32 %0, %1, %2"
            : "=v"(w32[n][hh])
            : "v"(p[n][2 * hh]), "v"(p[n][2 * hh + 1]));
    // redistribute to PV B-operand (verified r5): lane gets P[q=lr][k-slice]
    const int src0 = lr + ((lg & 1) << 5);
    const bool hi = (lg & 2) != 0;
    bf16x8 pa[2];
#pragma unroll
    for (int ks = 0; ks < 2; ks++) {
      unsigned a0 = __shfl((int)w32[2 * ks][0], src0, 64);
      unsigned a1 = __shfl((int)w32[2 * ks][1], src0, 64);
      unsigned a2 = __shfl((int)w32[2 * ks][0], src0 + 16, 64);
      unsigned a3 = __shfl((int)w32[2 * ks][1], src0 + 16, 64);
      unsigned b0 = __shfl((int)w32[2 * ks + 1][0], src0, 64);
      unsigned b1 = __shfl((int)w32[2 * ks + 1][1], src0, 64);
      unsigned b2 = __shfl((int)w32[2 * ks + 1][0], src0 + 16, 64);
      unsigned b3 = __shfl((int)w32[2 * ks + 1][1], src0 + 16, 64);
      union { unsigned int u[4]; bf16x8 v; } cv;
      cv.u[0] = hi ? b0 : a0;
      cv.u[1] = hi ? b1 : a1;
      cv.u[2] = hi ? b2 : a2;
      cv.u[3] = hi ? b3 : a3;
      pa[ks] = cv.v;
    }
    // PV: accT[nd][r] = O[qa][d = nd*16 + lg*4 + r]
    __builtin_amdgcn_s_setprio(1);
#pragma unroll
    for (int ks = 0; ks < 2; ks++)
#pragma unroll
      for (int nd = 0; nd < 4; nd++)
        accT[nd] = __builtin_amdgcn_mfma_f32_16x16x32_bf16(vb[nd][ks], pa[ks],
                                                           accT[nd], 0, 0, 0);
    __builtin_amdgcn_s_setprio(0);
    __syncthreads();  // staging of t+1 drained; all waves done reading buf
    buf ^= 1;
  }
#undef STAGE_TILES

  // epilogue: O[qa][h*64 + nd*16 + lg*4 + r]
  float inv = 1.0f / lrun;
#pragma unroll
  for (int nd = 0; nd < 4; nd++) {
    u16x4 o;
#pragma unroll
    for (int r = 0; r < 4; r++) o[r] = f2bf(accT[nd][r] * inv);
    *reinterpret_cast<u16x4*>(
        Og + ((size_t)(b * NS + qa)) * ND + h * DKH + nd * 16 + lg * 4) = o;
  }
}

// ---------------------------------------------------------------- launch ----
extern "C" void kernel_launch(void* const* d_in, const int* in_sizes, int n_in,
                              void* d_out, int out_size, void* d_ws, size_t ws_size,
                              hipStream_t stream) {
  (void)in_sizes; (void)n_in; (void)out_size; (void)ws_size;
  const float* query = (const float*)d_in[0];
  const float* key_  = (const float*)d_in[1];
  const float* value = (const float*)d_in[2];
  const int*   mask  = (const int*)d_in[3];
  const float* wq = (const float*)d_in[4];
  const float* bq = (const float*)d_in[5];
  const float* wk = (const float*)d_in[6];
  const float* bk = (const float*)d_in[7];
  const float* wv = (const float*)d_in[8];
  const float* bv = (const float*)d_in[9];
  const float* wo = (const float*)d_in[10];
  const float* bo = (const float*)d_in[11];
  float* out = (float*)d_out;

  char* ws = (char*)d_ws;
  const size_t SZX = (size_t)NB * NS * ND * 2;  // 8 MB (bf16 [4096,1024])
  const size_t SZW = (size_t)ND * ND * 2;       // 2 MB
  unsigned short* xq  = (unsigned short*)(ws);
  unsigned short* xk  = (unsigned short*)(ws + SZX);
  unsigned short* xv  = (unsigned short*)(ws + 2 * SZX);
  unsigned short* wqb = (unsigned short*)(ws + 3 * SZX);
  unsigned short* wkb = (unsigned short*)(ws + 3 * SZX + SZW);
  unsigned short* wvb = (unsigned short*)(ws + 3 * SZX + 2 * SZW);
  unsigned short* wob = (unsigned short*)(ws + 3 * SZX + 3 * SZW);
  unsigned short* Qb  = (unsigned short*)(ws + 3 * SZX + 4 * SZW);
  unsigned short* Kb  = (unsigned short*)(ws + 4 * SZX + 4 * SZW);
  unsigned short* Vt  = (unsigned short*)(ws + 5 * SZX + 4 * SZW);
  unsigned short* Ob  = (unsigned short*)(ws + 6 * SZX + 4 * SZW);
  unsigned long long* mb = (unsigned long long*)(ws + 7 * SZX + 4 * SZW);
  // total ws use: 7*8MB + 8MB + 1MB = 65 MB

  prep_kernel<<<2560, 256, 0, stream>>>(query, key_, value, wq, wk, wv, wo,
                                        xq, mask, mb);

  qkv_kernel<<<dim3(8, 32, 3), 256, 0, stream>>>(xq, xk, xv, wqb, wkb, wvb,
                                                 bq, bk, bv, Qb, Kb, Vt);
  attn_kernel<<<512, 512, 0, stream>>>(Qb, Kb, Vt, mb, Ob);
  outproj_kernel<<<dim3(8, 32), 512, 0, stream>>>(Ob, wob, bo, out);
}

// Round 11
// 278.554 us; speedup vs baseline: 1.7549x; 1.0127x over previous
//
#include <hip/hip_runtime.h>
#include <hip/hip_bf16.h>
#include <stdint.h>

// Problem constants: B=2, S=2048, D=1024, H=16, dk=64
#define NB 2
#define NS 2048
#define ND 1024
#define NH 16
#define DKH 64

typedef __attribute__((ext_vector_type(8))) short bf16x8;   // 8 bf16 = 4 VGPRs
typedef __attribute__((ext_vector_type(4))) float f32x4;
typedef __attribute__((ext_vector_type(8))) unsigned short u16x8;
typedef __attribute__((ext_vector_type(4))) unsigned short u16x4;

__device__ __forceinline__ unsigned short f2bf(float x) {
  union { float f; unsigned int u; } c; c.f = x;
  unsigned int u = c.u;
  unsigned int r = (u + 0x7fffu + ((u >> 16) & 1u)) >> 16;  // round-nearest-even
  return (unsigned short)r;
}

// async global->LDS, 16B per lane; LDS dest is wave-uniform base + lane*16
#define GLOAD_LDS16(gp, lp)                                                     \
  __builtin_amdgcn_global_load_lds(                                             \
      (const __attribute__((address_space(1))) void*)(gp),                      \
      (__attribute__((address_space(3))) void*)(lp), 16, 0, 0)

// ------------------------------------------------------------------ prep ----
// blocks [0,2048): fused fp32->bf16 of {query,key,value,wq,wk,wv,wo} into
// contiguous ws. blocks [2048,2560): mask [B,1,S,S] int32 -> bitmask.
__global__ __launch_bounds__(256) void prep_kernel(
    const float* __restrict__ s0, const float* __restrict__ s1,
    const float* __restrict__ s2, const float* __restrict__ s3,
    const float* __restrict__ s4, const float* __restrict__ s5,
    const float* __restrict__ s6, unsigned short* __restrict__ dst,
    const int* __restrict__ mask, unsigned long long* __restrict__ bits) {
  const int NIN = NB * NS * ND / 8;   // 524288 groups of 8
  const int NWT = ND * ND / 8;        // 131072
  const int TOT = 3 * NIN + 4 * NWT;  // 2097152
  if (blockIdx.x < 2048) {
    for (int i = blockIdx.x * blockDim.x + threadIdx.x; i < TOT;
         i += 2048 * 256) {
      const float* s; int off;
      if (i < NIN)            { s = s0; off = i; }
      else if (i < 2 * NIN)   { s = s1; off = i - NIN; }
      else if (i < 3 * NIN)   { s = s2; off = i - 2 * NIN; }
      else if (i < 3 * NIN + NWT)     { s = s3; off = i - 3 * NIN; }
      else if (i < 3 * NIN + 2 * NWT) { s = s4; off = i - (3 * NIN + NWT); }
      else if (i < 3 * NIN + 3 * NWT) { s = s5; off = i - (3 * NIN + 2 * NWT); }
      else                            { s = s6; off = i - (3 * NIN + 3 * NWT); }
      const float4* sp = reinterpret_cast<const float4*>(s) + (size_t)off * 2;
      float4 a = sp[0], b = sp[1];
      u16x8 o;
      o[0] = f2bf(a.x); o[1] = f2bf(a.y); o[2] = f2bf(a.z); o[3] = f2bf(a.w);
      o[4] = f2bf(b.x); o[5] = f2bf(b.y); o[6] = f2bf(b.z); o[7] = f2bf(b.w);
      reinterpret_cast<u16x8*>(dst)[i] = o;
    }
  } else {
    int i = (blockIdx.x - 2048) * blockDim.x + threadIdx.x;  // one u64/thread
    const int4* p = reinterpret_cast<const int4*>(mask + (size_t)i * 64);
    unsigned long long w = 0;
#pragma unroll
    for (int j = 0; j < 16; j++) {
      int4 v = p[j];
      unsigned long long nib = (v.x ? 1ull : 0) | (v.y ? 2ull : 0) |
                               (v.z ? 4ull : 0) | (v.w ? 8ull : 0);
      w |= nib << (j * 4);
    }
    bits[i] = w;
  }
}

// ------------------------------------------------------------- GEMM core ----
// C[BMxBN] = A[BMxK] * Bt[BNxK]^T ; K = 1024, BK=64, global_load_lds w=16.
// THREADS/64 waves arranged (WRN x WCN); wave tile = AM*16 x AN*16.
// SWAP=true computes D^T fragments (operands swapped) for the V-transpose path.
template <bool SWAP, int THREADS, int WCN, int AM, int AN>
__device__ __forceinline__ void gemm_core(const unsigned short* __restrict__ A,
                                          const unsigned short* __restrict__ Bt,
                                          int m0, int n0,
                                          unsigned short* As, unsigned short* Bs,
                                          f32x4 (&acc)[AM][AN]) {
  constexpr int NWAVE = THREADS / 64;
  constexpr int WRN = NWAVE / WCN;
  constexpr int BM = WRN * AM * 16;
  constexpr int BN = WCN * AN * 16;
  constexpr int JA = BM * 64 / (THREADS * 8);
  constexpr int JB = BN * 64 / (THREADS * 8);
  const int tid = threadIdx.x;
  const int w = tid >> 6;
  const int l = tid & 63;
  const int wr = w / WCN, wc = w % WCN;
  const int lr = l & 15, lg = l >> 4;

#pragma unroll
  for (int i = 0; i < AM; i++)
#pragma unroll
    for (int j = 0; j < AN; j++) acc[i][j] = (f32x4){0.f, 0.f, 0.f, 0.f};

  for (int k0 = 0; k0 < ND; k0 += 64) {
    __syncthreads();  // previous tile's compute done before overwrite
#pragma unroll
    for (int j = 0; j < JA; j++) {
      int flat = j * (THREADS * 8) + tid * 8;  // elem index in BMx64 tile
      int row = flat >> 6, col = flat & 63;
      GLOAD_LDS16(A + (size_t)(m0 + row) * ND + k0 + col,
                  As + j * (THREADS * 8) + w * 512);
    }
#pragma unroll
    for (int j = 0; j < JB; j++) {
      int flat = j * (THREADS * 8) + tid * 8;
      int row = flat >> 6, col = flat & 63;
      GLOAD_LDS16(Bt + (size_t)(n0 + row) * ND + k0 + col,
                  Bs + j * (THREADS * 8) + w * 512);
    }
    __syncthreads();  // compiler emits vmcnt(0) drain before barrier
#pragma unroll
    for (int ks = 0; ks < 2; ks++) {
      bf16x8 av[AM], bv[AN];
#pragma unroll
      for (int mi = 0; mi < AM; mi++)
        av[mi] = *reinterpret_cast<const bf16x8*>(
            As + (wr * (AM * 16) + mi * 16 + lr) * 64 + ks * 32 + lg * 8);
#pragma unroll
      for (int ni = 0; ni < AN; ni++)
        bv[ni] = *reinterpret_cast<const bf16x8*>(
            Bs + (wc * (AN * 16) + ni * 16 + lr) * 64 + ks * 32 + lg * 8);
#pragma unroll
      for (int mi = 0; mi < AM; mi++)
#pragma unroll
        for (int ni = 0; ni < AN; ni++)
          acc[mi][ni] = SWAP
              ? __builtin_amdgcn_mfma_f32_16x16x32_bf16(bv[ni], av[mi], acc[mi][ni], 0, 0, 0)
              : __builtin_amdgcn_mfma_f32_16x16x32_bf16(av[mi], bv[ni], acc[mi][ni], 0, 0, 0);
    }
  }
}

// QKV projection: z=0 Q (pre-scaled by 1/sqrt(dk)), z=1 K (store [B,H,S,dk]);
// z=2 V (store transposed [B,H,dk,S]).
// R11: launch_bounds(256,3) — grid 768 = 3 blocks/CU; cap VGPR so the 3rd
// block is resident and overlaps the per-K-step barrier drain.
__global__ __launch_bounds__(256, 3) void qkv_kernel(
    const unsigned short* __restrict__ Xq, const unsigned short* __restrict__ Xk,
    const unsigned short* __restrict__ Xv, const unsigned short* __restrict__ Wq,
    const unsigned short* __restrict__ Wk, const unsigned short* __restrict__ Wv,
    const float* __restrict__ bq, const float* __restrict__ bk,
    const float* __restrict__ bv, unsigned short* __restrict__ Qo,
    unsigned short* __restrict__ Ko, unsigned short* __restrict__ Vt) {
  __shared__ __align__(16) unsigned short As[128 * 64];
  __shared__ __align__(16) unsigned short Bs[128 * 64];
  const int z = blockIdx.z;
  const unsigned short* X = (z == 0) ? Xq : (z == 1) ? Xk : Xv;
  const unsigned short* W = (z == 0) ? Wq : (z == 1) ? Wk : Wv;
  const float* bias = (z == 0) ? bq : (z == 1) ? bk : bv;
  const int m0 = blockIdx.y * 128, n0 = blockIdx.x * 128;
  const int tid = threadIdx.x;
  const int w = tid >> 6, l = tid & 63;
  const int wr = w >> 1, wc = w & 1, lr = l & 15, lg = l >> 4;
  f32x4 acc[4][4];

  if (z < 2) {
    gemm_core<false, 256, 2, 4, 4>(X, W, m0, n0, As, Bs, acc);
    unsigned short* O = (z == 0) ? Qo : Ko;
    const float scl = (z == 0) ? 0.125f : 1.0f;  // fold 1/sqrt(64) into Q
#pragma unroll
    for (int mi = 0; mi < 4; mi++)
#pragma unroll
      for (int ni = 0; ni < 4; ni++)
#pragma unroll
        for (int r = 0; r < 4; r++) {
          int mrow = m0 + wr * 64 + mi * 16 + lg * 4 + r;   // b*S+s
          int ncol = n0 + wc * 64 + ni * 16 + lr;           // h*dk+d
          float y = (acc[mi][ni][r] + bias[ncol]) * scl;
          int bb = mrow >> 11, s = mrow & 2047, hh = ncol >> 6, d = ncol & 63;
          O[(((size_t)(bb * NH + hh)) * NS + s) * DKH + d] = f2bf(y);
        }
  } else {
    gemm_core<true, 256, 2, 4, 4>(X, W, m0, n0, As, Bs, acc);  // D^T fragments
#pragma unroll
    for (int mi = 0; mi < 4; mi++)
#pragma unroll
      for (int ni = 0; ni < 4; ni++)
#pragma unroll
        for (int r = 0; r < 4; r++) {
          int ncol = n0 + wc * 64 + ni * 16 + lg * 4 + r;   // output feature
          int mrow = m0 + wr * 64 + mi * 16 + lr;           // b*S+s (lane-consec)
          float y = acc[mi][ni][r] + bias[ncol];
          int bb = mrow >> 11, s = mrow & 2047, hh = ncol >> 6, d = ncol & 63;
          Vt[(((size_t)(bb * NH + hh)) * DKH + d) * NS + s] = f2bf(y);
        }
  }
}

// output projection: out = O @ wo^T + bo, fp32 out.
// R11: 64x128 tile @ 256 threads (4 waves 1x4), grid (8,64)=512 = 2 blocks/CU
// for cross-block barrier overlap (was 128x128@512, 1 block/CU).
__global__ __launch_bounds__(256, 2) void outproj_kernel(
    const unsigned short* __restrict__ Oin, const unsigned short* __restrict__ Wo,
    const float* __restrict__ bo, float* __restrict__ out) {
  __shared__ __align__(16) unsigned short As[64 * 64];
  __shared__ __align__(16) unsigned short Bs[128 * 64];
  const int m0 = blockIdx.y * 64, n0 = blockIdx.x * 128;
  const int tid = threadIdx.x;
  const int w = tid >> 6, l = tid & 63;
  const int wr = 0, wc = w & 3, lr = l & 15, lg = l >> 4;
  f32x4 acc[4][2];
  gemm_core<false, 256, 4, 4, 2>(Oin, Wo, m0, n0, As, Bs, acc);
#pragma unroll
  for (int mi = 0; mi < 4; mi++)
#pragma unroll
    for (int ni = 0; ni < 2; ni++)
#pragma unroll
      for (int r = 0; r < 4; r++) {
        int mrow = m0 + wr * 64 + mi * 16 + lg * 4 + r;
        int ncol = n0 + wc * 32 + ni * 16 + lr;
        out[(size_t)mrow * ND + ncol] = acc[mi][ni][r] + bo[ncol];
      }
}

// ----------------------------------------------------------- attention ------
// UNCHANGED from R10 (79.7 µs control): Block = (b, h, 128 q-rows); 8 waves x
// 16 q-rows (512 threads). K and V^T tiles staged in LDS w/ XOR swizzle,
// double-buffered. Swapped QK^T -> in-register softmax; defer-max, fused
// exp2, cvt_pk pack; P redistributed to PV B-operand via 16 shuffles.
__global__ __launch_bounds__(512, 2) void attn_kernel(
    const unsigned short* __restrict__ Qg, const unsigned short* __restrict__ Kg,
    const unsigned short* __restrict__ Vtg,
    const unsigned long long* __restrict__ mbits,
    unsigned short* __restrict__ Og) {
  __shared__ __align__(16) unsigned short Ks[2][64 * 64];
  __shared__ __align__(16) unsigned short Vs[2][64 * 64];
  const int tid = threadIdx.x;
  const int w = tid >> 6, l = tid & 63;  // 8 waves
  const int lr = l & 15, lg = l >> 4;
  // head-major decode: head h always lands on XCD h%8 (blockIdx RR over XCDs)
  const int lin = blockIdx.x;          // 512 blocks
  const int h = lin & 15;
  const int rest = lin >> 4;           // [0,32)
  const int qblk = rest & 15;          // 16 q-blocks of 128 rows
  const int b = rest >> 4;
  const int qbase = qblk * 128 + w * 16;
  const int qa = qbase + lr;           // this lane's q-row

  const unsigned short* Qh = Qg + ((size_t)(b * NH + h)) * NS * DKH;
  const unsigned short* Kh = Kg + ((size_t)(b * NH + h)) * NS * DKH;
  const unsigned short* Vth = Vtg + ((size_t)(b * NH + h)) * DKH * NS;
  const unsigned long long* mrow = mbits + (size_t)(b * NS + qa) * (NS / 64);

  // Q fragments (Q pre-scaled by 1/sqrt(dk) in qkv)
  bf16x8 aQ[2];
#pragma unroll
  for (int ks = 0; ks < 2; ks++)
    aQ[ks] = *reinterpret_cast<const bf16x8*>(
        Qh + (size_t)qa * DKH + ks * 32 + lg * 8);

  f32x4 accT[4];
#pragma unroll
  for (int nd = 0; nd < 4; nd++) accT[nd] = (f32x4){0.f, 0.f, 0.f, 0.f};
  float mrun = -3.0e38f, lrun = 0.f;

  // cooperative staging: 8KB tile = 512 chunks of 16B; 512 threads x 1 inst.
  // pre-swizzled SOURCE (chunk-in-row ^= row&7) + linear LDS dest + swizzled
  // ds_read => net identity (rule: both-sides-or-neither).
#define STAGE_TILES(bufi, kk0)                                                  \
  {                                                                             \
    int row = tid >> 3;                                                         \
    int cr = (tid & 7) ^ (row & 7);                                             \
    GLOAD_LDS16(Kh + (size_t)((kk0) + row) * DKH + cr * 8,                      \
                &Ks[bufi][(size_t)w * 512]);                                    \
    GLOAD_LDS16(Vth + (size_t)row * NS + (kk0) + cr * 8,                        \
                &Vs[bufi][(size_t)w * 512]);                                    \
  }

  STAGE_TILES(0, 0)
  __syncthreads();  // compiler drains vmcnt before barrier
  int buf = 0;
  const float L2E = 1.4426950408889634f;

  for (int t = 0; t < NS / 64; t++) {
    const int kk0 = t * 64;
    if (t < NS / 64 - 1) STAGE_TILES(buf ^ 1, kk0 + 64)
    unsigned long long w64 = mrow[t];
    // K fragments from LDS
    bf16x8 kb[4][2];
#pragma unroll
    for (int n = 0; n < 4; n++)
#pragma unroll
      for (int ks = 0; ks < 2; ks++)
        kb[n][ks] = *reinterpret_cast<const bf16x8*>(
            &Ks[buf][(size_t)(n * 16 + lr) * 64 +
                     (size_t)(((ks * 4 + lg) ^ (lr & 7)) * 8)]);
    // QK^T: sT[n][r] = S[qa][kk0 + n*16 + lg*4 + r]
    f32x4 sT[4];
#pragma unroll
    for (int n = 0; n < 4; n++) sT[n] = (f32x4){0.f, 0.f, 0.f, 0.f};
    __builtin_amdgcn_s_setprio(1);
#pragma unroll
    for (int ks = 0; ks < 2; ks++)
#pragma unroll
      for (int n = 0; n < 4; n++)
        sT[n] = __builtin_amdgcn_mfma_f32_16x16x32_bf16(kb[n][ks], aQ[ks],
                                                        sT[n], 0, 0, 0);
    __builtin_amdgcn_s_setprio(0);
    // V fragments (LDS reads issued early; consumed after softmax)
    bf16x8 vb[4][2];
#pragma unroll
    for (int nd = 0; nd < 4; nd++)
#pragma unroll
      for (int ks = 0; ks < 2; ks++)
        vb[nd][ks] = *reinterpret_cast<const bf16x8*>(
            &Vs[buf][(size_t)(nd * 16 + lr) * 64 +
                     (size_t)(((ks * 4 + lg) ^ (lr & 7)) * 8)]);

    if (w64 != ~0ull) {
      unsigned long long wsh = w64 >> (lg * 4);
#pragma unroll
      for (int n = 0; n < 4; n++)
#pragma unroll
        for (int r = 0; r < 4; r++)
          if (!((wsh >> (n * 16 + r)) & 1ull)) sT[n][r] = -1e9f;
    }
    // online softmax, per-lane stats (one q-row per lane)
    float m0 = fmaxf(fmaxf(sT[0][0], sT[0][1]), fmaxf(sT[0][2], sT[0][3]));
    float m1 = fmaxf(fmaxf(sT[1][0], sT[1][1]), fmaxf(sT[1][2], sT[1][3]));
    float m2 = fmaxf(fmaxf(sT[2][0], sT[2][1]), fmaxf(sT[2][2], sT[2][3]));
    float m3 = fmaxf(fmaxf(sT[3][0], sT[3][1]), fmaxf(sT[3][2], sT[3][3]));
    float mx = fmaxf(fmaxf(m0, m1), fmaxf(m2, m3));
    mx = fmaxf(mx, __shfl_xor(mx, 16));
    mx = fmaxf(mx, __shfl_xor(mx, 32));
    // defer-max (T13): skip rescale when tile max within THR of running max
    float nm;
    if (__all(mx <= mrun + 8.0f)) {
      nm = mrun;
    } else {
      nm = fmaxf(mrun, mx);
      float corr = __expf(mrun - nm);
      mrun = nm;
      lrun *= corr;
#pragma unroll
      for (int nd = 0; nd < 4; nd++) accT[nd] *= corr;
    }
    // p = exp2(s*log2e - nm*log2e): 1 fma + 1 exp per element
    const float nmL = nm * L2E;
    float p[4][4];
    float psum = 0.f;
#pragma unroll
    for (int n = 0; n < 4; n++) {
#pragma unroll
      for (int r = 0; r < 4; r++)
        p[n][r] = __builtin_amdgcn_exp2f(__builtin_fmaf(sT[n][r], L2E, -nmL));
      psum += (p[n][0] + p[n][1]) + (p[n][2] + p[n][3]);
    }
    psum += __shfl_xor(psum, 16);
    psum += __shfl_xor(psum, 32);
    lrun += psum;
    // pack P pairs to bf16 words via HW cvt: w32[n][hh] = (p[2hh], p[2hh+1])
    unsigned int w32[4][2];
#pragma unroll
    for (int n = 0; n < 4; n++)
#pragma unroll
      for (int hh = 0; hh < 2; hh++)
        asm("v_cvt_pk_bf16_f32 %0, %1, %2"
            : "=v"(w32[n][hh])
            : "v"(p[n][2 * hh]), "v"(p[n][2 * hh + 1]));
    // redistribute to PV B-operand (verified r5): lane gets P[q=lr][k-slice]
    const int src0 = lr + ((lg & 1) << 5);
    const bool hi = (lg & 2) != 0;
    bf16x8 pa[2];
#pragma unroll
    for (int ks = 0; ks < 2; ks++) {
      unsigned a0 = __shfl((int)w32[2 * ks][0], src0, 64);
      unsigned a1 = __shfl((int)w32[2 * ks][1], src0, 64);
      unsigned a2 = __shfl((int)w32[2 * ks][0], src0 + 16, 64);
      unsigned a3 = __shfl((int)w32[2 * ks][1], src0 + 16, 64);
      unsigned b0 = __shfl((int)w32[2 * ks + 1][0], src0, 64);
      unsigned b1 = __shfl((int)w32[2 * ks + 1][1], src0, 64);
      unsigned b2 = __shfl((int)w32[2 * ks + 1][0], src0 + 16, 64);
      unsigned b3 = __shfl((int)w32[2 * ks + 1][1], src0 + 16, 64);
      union { unsigned int u[4]; bf16x8 v; } cv;
      cv.u[0] = hi ? b0 : a0;
      cv.u[1] = hi ? b1 : a1;
      cv.u[2] = hi ? b2 : a2;
      cv.u[3] = hi ? b3 : a3;
      pa[ks] = cv.v;
    }
    // PV: accT[nd][r] = O[qa][d = nd*16 + lg*4 + r]
    __builtin_amdgcn_s_setprio(1);
#pragma unroll
    for (int ks = 0; ks < 2; ks++)
#pragma unroll
      for (int nd = 0; nd < 4; nd++)
        accT[nd] = __builtin_amdgcn_mfma_f32_16x16x32_bf16(vb[nd][ks], pa[ks],
                                                           accT[nd], 0, 0, 0);
    __builtin_amdgcn_s_setprio(0);
    __syncthreads();  // staging of t+1 drained; all waves done reading buf
    buf ^= 1;
  }
#undef STAGE_TILES

  // epilogue: O[qa][h*64 + nd*16 + lg*4 + r]
  float inv = 1.0f / lrun;
#pragma unroll
  for (int nd = 0; nd < 4; nd++) {
    u16x4 o;
#pragma unroll
    for (int r = 0; r < 4; r++) o[r] = f2bf(accT[nd][r] * inv);
    *reinterpret_cast<u16x4*>(
        Og + ((size_t)(b * NS + qa)) * ND + h * DKH + nd * 16 + lg * 4) = o;
  }
}

// ---------------------------------------------------------------- launch ----
extern "C" void kernel_launch(void* const* d_in, const int* in_sizes, int n_in,
                              void* d_out, int out_size, void* d_ws, size_t ws_size,
                              hipStream_t stream) {
  (void)in_sizes; (void)n_in; (void)out_size; (void)ws_size;
  const float* query = (const float*)d_in[0];
  const float* key_  = (const float*)d_in[1];
  const float* value = (const float*)d_in[2];
  const int*   mask  = (const int*)d_in[3];
  const float* wq = (const float*)d_in[4];
  const float* bq = (const float*)d_in[5];
  const float* wk = (const float*)d_in[6];
  const float* bk = (const float*)d_in[7];
  const float* wv = (const float*)d_in[8];
  const float* bv = (const float*)d_in[9];
  const float* wo = (const float*)d_in[10];
  const float* bo = (const float*)d_in[11];
  float* out = (float*)d_out;

  char* ws = (char*)d_ws;
  const size_t SZX = (size_t)NB * NS * ND * 2;  // 8 MB (bf16 [4096,1024])
  const size_t SZW = (size_t)ND * ND * 2;       // 2 MB
  unsigned short* xq  = (unsigned short*)(ws);
  unsigned short* xk  = (unsigned short*)(ws + SZX);
  unsigned short* xv  = (unsigned short*)(ws + 2 * SZX);
  unsigned short* wqb = (unsigned short*)(ws + 3 * SZX);
  unsigned short* wkb = (unsigned short*)(ws + 3 * SZX + SZW);
  unsigned short* wvb = (unsigned short*)(ws + 3 * SZX + 2 * SZW);
  unsigned short* wob = (unsigned short*)(ws + 3 * SZX + 3 * SZW);
  unsigned short* Qb  = (unsigned short*)(ws + 3 * SZX + 4 * SZW);
  unsigned short* Kb  = (unsigned short*)(ws + 4 * SZX + 4 * SZW);
  unsigned short* Vt  = (unsigned short*)(ws + 5 * SZX + 4 * SZW);
  unsigned short* Ob  = (unsigned short*)(ws + 6 * SZX + 4 * SZW);
  unsigned long long* mb = (unsigned long long*)(ws + 7 * SZX + 4 * SZW);
  // total ws use: 7*8MB + 8MB + 1MB = 65 MB

  prep_kernel<<<2560, 256, 0, stream>>>(query, key_, value, wq, wk, wv, wo,
                                        xq, mask, mb);

  qkv_kernel<<<dim3(8, 32, 3), 256, 0, stream>>>(xq, xk, xv, wqb, wkb, wvb,
                                                 bq, bk, bv, Qb, Kb, Vt);
  attn_kernel<<<512, 512, 0, stream>>>(Qb, Kb, Vt, mb, Ob);
  outproj_kernel<<<dim3(8, 64), 256, 0, stream>>>(Ob, wob, bo, out);
}